// Round 3
// baseline (2237.114 us; speedup 1.0000x reference)
//
#include <hip/hip_runtime.h>

// GCN 2-layer:  out = dinv ⊙ (A · (dinv ⊙ (relu(dinv ⊙ (A · (dinv ⊙ (x@W1))) + b1) @ W2))) + b2
// A = adjacency (dst<-src) + I.  deg counted over dst incl. self-loop.

constexpr int DIN = 128;

// ---- degree / norm ---------------------------------------------------------
__global__ void init_deg_k(int* __restrict__ deg, int n) {
    int i = blockIdx.x * 256 + threadIdx.x;
    if (i < n) deg[i] = 1;                      // self-loop
}

__global__ void count_deg_k(const int* __restrict__ dst, int* __restrict__ deg, int e) {
    int i = blockIdx.x * 256 + threadIdx.x;
    if (i < e) atomicAdd(&deg[dst[i]], 1);
}

__global__ void dinv_k(const int* __restrict__ deg, float* __restrict__ dinv, int n) {
    int i = blockIdx.x * 256 + threadIdx.x;
    if (i < n) dinv[i] = rsqrtf((float)deg[i]);
}

// ---- fused GEMM + row scale ------------------------------------------------
// G  = dinv[:,None] * (X @ W)      (also duplicated into G2 = self-loop init of agg)
// X: [N,128], W: [128,DOUT] row-major.  TM=64 rows per block, 256 threads.
template <int DOUT>
__global__ __launch_bounds__(256) void gemm_scale_k(
    const float* __restrict__ X, const float* __restrict__ W,
    const float* __restrict__ dinv,
    float* __restrict__ G, float* __restrict__ G2, int N)
{
    constexpr int TM = 64;
    constexpr int C4 = DOUT / 4;        // float4 cols
    constexpr int GROUPS = 256 / C4;    // row groups: 8 (DOUT=128) / 16 (DOUT=64)
    constexpr int RPT = TM / GROUPS;    // rows per thread: 8 / 4

    __shared__ float sW[DIN * DOUT];
    __shared__ float sX[TM * DIN];

    const int tid  = threadIdx.x;
    const int base = blockIdx.x * TM;

    for (int idx = tid; idx < DIN * DOUT / 4; idx += 256)
        reinterpret_cast<float4*>(sW)[idx] = reinterpret_cast<const float4*>(W)[idx];

    for (int idx = tid; idx < TM * DIN / 4; idx += 256) {
        int row  = idx / (DIN / 4);
        int grow = base + row;
        float4 v = make_float4(0.f, 0.f, 0.f, 0.f);
        if (grow < N)
            v = reinterpret_cast<const float4*>(X)[(size_t)grow * (DIN / 4) + (idx % (DIN / 4))];
        reinterpret_cast<float4*>(sX)[idx] = v;
    }
    __syncthreads();

    const int cq = tid % C4;            // which float4 of the output row
    const int rg = tid / C4;            // row group

    float4 acc[RPT];
#pragma unroll
    for (int r = 0; r < RPT; ++r) acc[r] = make_float4(0.f, 0.f, 0.f, 0.f);

#pragma unroll 4
    for (int k = 0; k < DIN; ++k) {
        float4 w = reinterpret_cast<const float4*>(sW)[k * C4 + cq];
#pragma unroll
        for (int r = 0; r < RPT; ++r) {
            float xv = sX[(rg + r * GROUPS) * DIN + k];
            acc[r].x = fmaf(xv, w.x, acc[r].x);
            acc[r].y = fmaf(xv, w.y, acc[r].y);
            acc[r].z = fmaf(xv, w.z, acc[r].z);
            acc[r].w = fmaf(xv, w.w, acc[r].w);
        }
    }

#pragma unroll
    for (int r = 0; r < RPT; ++r) {
        int row = base + rg + r * GROUPS;
        if (row < N) {
            float dv = dinv[row];
            float4 o = make_float4(acc[r].x * dv, acc[r].y * dv, acc[r].z * dv, acc[r].w * dv);
            reinterpret_cast<float4*>(G )[(size_t)row * C4 + cq] = o;
            reinterpret_cast<float4*>(G2)[(size_t)row * C4 + cq] = o;
        }
    }
}

// ---- edge scatter: AGG[dst] += G[src] --------------------------------------
template <int D>
__global__ void scatter_add_k(const int* __restrict__ src, const int* __restrict__ dst,
                              const float* __restrict__ G, float* __restrict__ AGG, int E)
{
    constexpr int Q = D / 4;            // float4 lanes per edge (32 / 16)
    int t = blockIdx.x * 256 + threadIdx.x;
    int e = t / Q;
    int q = t % Q;
    if (e >= E) return;
    int s = src[e];
    int d = dst[e];
    float4 v = *reinterpret_cast<const float4*>(G + (size_t)s * D + q * 4);
    float* a = AGG + (size_t)d * D + q * 4;
    atomicAdd(a + 0, v.x);
    atomicAdd(a + 1, v.y);
    atomicAdd(a + 2, v.z);
    atomicAdd(a + 3, v.w);
}

// ---- x2 = relu(dinv*agg + b1) ----------------------------------------------
__global__ void relu_bias_k(const float* __restrict__ agg, const float* __restrict__ dinv,
                            const float* __restrict__ b, float* __restrict__ out, int n4)
{
    // D = 128 fixed; one float4 per thread
    int t = blockIdx.x * 256 + threadIdx.x;
    if (t >= n4) return;
    int row = t / (DIN / 4);
    int f4  = t % (DIN / 4);
    float dv = dinv[row];
    float4 v = reinterpret_cast<const float4*>(agg)[t];
    float4 bb = reinterpret_cast<const float4*>(b)[f4];
    float4 o;
    o.x = fmaxf(dv * v.x + bb.x, 0.f);
    o.y = fmaxf(dv * v.y + bb.y, 0.f);
    o.z = fmaxf(dv * v.z + bb.z, 0.f);
    o.w = fmaxf(dv * v.w + bb.w, 0.f);
    reinterpret_cast<float4*>(out)[t] = o;
}

// ---- out = dinv*out + b2 (in place, D=64) ----------------------------------
__global__ void final_k(float* __restrict__ out, const float* __restrict__ dinv,
                        const float* __restrict__ b, int n4)
{
    int t = blockIdx.x * 256 + threadIdx.x;
    if (t >= n4) return;
    int row = t / (64 / 4);
    int f4  = t % (64 / 4);
    float dv = dinv[row];
    float4 v  = reinterpret_cast<float4*>(out)[t];
    float4 bb = reinterpret_cast<const float4*>(b)[f4];
    v.x = dv * v.x + bb.x;
    v.y = dv * v.y + bb.y;
    v.z = dv * v.z + bb.z;
    v.w = dv * v.w + bb.w;
    reinterpret_cast<float4*>(out)[t] = v;
}

static inline size_t align256(size_t x) { return (x + 255) & ~size_t(255); }

extern "C" void kernel_launch(void* const* d_in, const int* in_sizes, int n_in,
                              void* d_out, int out_size, void* d_ws, size_t ws_size,
                              hipStream_t stream) {
    const float* e_prev = (const float*)d_in[0];
    const int*   eidx   = (const int*)d_in[1];
    const float* W1     = (const float*)d_in[2];
    const float* b1     = (const float*)d_in[3];
    const float* W2     = (const float*)d_in[4];
    const float* b2     = (const float*)d_in[5];

    const int dh   = in_sizes[3];            // 128
    const int dout = in_sizes[5];            // 64
    const int din  = in_sizes[2] / dh;       // 128
    const int N    = in_sizes[0] / din;      // 50000
    const int E    = in_sizes[1] / 2;        // 800000
    (void)dh; (void)dout;

    const int* src = eidx;
    const int* dst = eidx + E;

    // workspace layout
    char* ws = (char*)d_ws;
    size_t off = 0;
    int*   deg  = (int*)(ws + off);  off = align256(off + (size_t)N * 4);
    float* dinv = (float*)(ws + off); off = align256(off + (size_t)N * 4);
    float* bufA = (float*)(ws + off); off = align256(off + (size_t)N * DIN * 4);
    float* bufB = (float*)(ws + off); off = align256(off + (size_t)N * DIN * 4);
    (void)ws_size;

    float* outp = (float*)d_out;

    const int T = 256;
    // 1) degree (init=1 for self loop) + dinv
    init_deg_k<<<(N + T - 1) / T, T, 0, stream>>>(deg, N);
    count_deg_k<<<(E + T - 1) / T, T, 0, stream>>>(dst, deg, E);
    dinv_k<<<(N + T - 1) / T, T, 0, stream>>>(deg, dinv, N);

    // 2) layer 1: g1 = dinv * (x @ W1) -> bufA ; agg1 init = g1 -> bufB
    gemm_scale_k<128><<<(N + 63) / 64, T, 0, stream>>>(e_prev, W1, dinv, bufA, bufB, N);

    // 3) scatter: agg1[dst] += g1[src]
    {
        int threads_total = E * (128 / 4);
        scatter_add_k<128><<<(threads_total + T - 1) / T, T, 0, stream>>>(src, dst, bufA, bufB, E);
    }

    // 4) x2 = relu(dinv*agg1 + b1) -> bufA
    relu_bias_k<<<((N * DIN / 4) + T - 1) / T, T, 0, stream>>>(bufB, dinv, b1, bufA, N * DIN / 4);

    // 5) layer 2: g2 = dinv * (x2 @ W2) -> bufB ; agg2 init = g2 -> d_out
    gemm_scale_k<64><<<(N + 63) / 64, T, 0, stream>>>(bufA, W2, dinv, bufB, outp, N);

    // 6) scatter: agg2[dst] += g2[src]
    {
        int threads_total = E * (64 / 4);
        scatter_add_k<64><<<(threads_total + T - 1) / T, T, 0, stream>>>(src, dst, bufB, outp, E);
    }

    // 7) out = dinv*out + b2
    final_k<<<((N * 64 / 4) + T - 1) / T, T, 0, stream>>>(outp, dinv, b2, N * 64 / 4);
}

// Round 4
// 410.839 us; speedup vs baseline: 5.4452x; 5.4452x over previous
//
#include <hip/hip_runtime.h>

// GCN 2-layer via CSR gather (no float atomics):
// out = dinv ⊙ (A · (dinv ⊙ (relu(dinv ⊙ (A · (dinv ⊙ (x@W1))) + b1) @ W2))) + b2
// A = adjacency (dst<-src) + I.  dinv[src] folded into G rows pre-aggregation,
// dinv[dst] applied in gather epilogue; self-loop = own G row.

constexpr int DIN = 128;

// ---- small utility kernels -------------------------------------------------
__global__ void zero_int_k(int* __restrict__ p, int n) {
    int i = blockIdx.x * 256 + threadIdx.x;
    if (i < n) p[i] = 0;
}

__global__ void count_deg_k(const int* __restrict__ dst, int* __restrict__ cnt, int e) {
    int i = blockIdx.x * 256 + threadIdx.x;
    if (i < e) atomicAdd(&cnt[dst[i]], 1);
}

__global__ void dinv_k(const int* __restrict__ cnt, float* __restrict__ dinv, int n) {
    int i = blockIdx.x * 256 + threadIdx.x;
    if (i < n) dinv[i] = rsqrtf((float)cnt[i] + 1.0f);   // +1 self-loop
}

// single-block exclusive scan: rowptr[0..n] from cnt[0..n-1]
__global__ __launch_bounds__(1024) void scan_k(const int* __restrict__ cnt,
                                               int* __restrict__ rowptr, int n) {
    __shared__ int part[1024];
    const int t = threadIdx.x;
    const int chunk = (n + 1023) / 1024;
    const int lo = t * chunk;
    const int hi = min(lo + chunk, n);
    int s = 0;
    for (int k = lo; k < hi; ++k) s += cnt[k];
    part[t] = s;
    __syncthreads();
    for (int off = 1; off < 1024; off <<= 1) {
        int v = (t >= off) ? part[t - off] : 0;
        __syncthreads();
        part[t] += v;
        __syncthreads();
    }
    int run = (t == 0) ? 0 : part[t - 1];
    for (int k = lo; k < hi; ++k) { rowptr[k] = run; run += cnt[k]; }
    if (t == 1023) rowptr[n] = part[1023];
}

__global__ void fill_k(const int* __restrict__ src, const int* __restrict__ dst,
                       const int* __restrict__ rowptr, int* __restrict__ cur,
                       int* __restrict__ col, int e) {
    int i = blockIdx.x * 256 + threadIdx.x;
    if (i >= e) return;
    int d = dst[i];
    int pos = rowptr[d] + atomicAdd(&cur[d], 1);
    col[pos] = src[i];
}

// ---- fused GEMM + row scale:  G = dinv[:,None] * (X @ W) -------------------
template <int DOUT>
__global__ __launch_bounds__(256) void gemm_scale_k(
    const float* __restrict__ X, const float* __restrict__ W,
    const float* __restrict__ dinv, float* __restrict__ G, int N)
{
    constexpr int TM = 64;
    constexpr int C4 = DOUT / 4;
    constexpr int GROUPS = 256 / C4;
    constexpr int RPT = TM / GROUPS;

    __shared__ float sW[DIN * DOUT];
    __shared__ float sX[TM * DIN];

    const int tid  = threadIdx.x;
    const int base = blockIdx.x * TM;

    for (int idx = tid; idx < DIN * DOUT / 4; idx += 256)
        reinterpret_cast<float4*>(sW)[idx] = reinterpret_cast<const float4*>(W)[idx];

    for (int idx = tid; idx < TM * DIN / 4; idx += 256) {
        int row  = idx / (DIN / 4);
        int grow = base + row;
        float4 v = make_float4(0.f, 0.f, 0.f, 0.f);
        if (grow < N)
            v = reinterpret_cast<const float4*>(X)[(size_t)grow * (DIN / 4) + (idx % (DIN / 4))];
        reinterpret_cast<float4*>(sX)[idx] = v;
    }
    __syncthreads();

    const int cq = tid % C4;
    const int rg = tid / C4;

    float4 acc[RPT];
#pragma unroll
    for (int r = 0; r < RPT; ++r) acc[r] = make_float4(0.f, 0.f, 0.f, 0.f);

#pragma unroll 4
    for (int k = 0; k < DIN; ++k) {
        float4 w = reinterpret_cast<const float4*>(sW)[k * C4 + cq];
#pragma unroll
        for (int r = 0; r < RPT; ++r) {
            float xv = sX[(rg + r * GROUPS) * DIN + k];
            acc[r].x = fmaf(xv, w.x, acc[r].x);
            acc[r].y = fmaf(xv, w.y, acc[r].y);
            acc[r].z = fmaf(xv, w.z, acc[r].z);
            acc[r].w = fmaf(xv, w.w, acc[r].w);
        }
    }

#pragma unroll
    for (int r = 0; r < RPT; ++r) {
        int row = base + rg + r * GROUPS;
        if (row < N) {
            float dv = dinv[row];
            float4 o = make_float4(acc[r].x * dv, acc[r].y * dv, acc[r].z * dv, acc[r].w * dv);
            reinterpret_cast<float4*>(G)[(size_t)row * C4 + cq] = o;
        }
    }
}

// ---- gather: one wave per node --------------------------------------------
// out[i] = op( dinv[i] * (G[i] + sum_{j in CSR row i} G[col[j]]) + bias )
template <int D, bool RELU>
__global__ __launch_bounds__(256) void gather_k(
    const float* __restrict__ G, const int* __restrict__ rowptr,
    const int* __restrict__ col, const float* __restrict__ dinv,
    const float* __restrict__ bias, float* __restrict__ out, int N)
{
    const int wave = (blockIdx.x * 256 + threadIdx.x) >> 6;
    const int lane = threadIdx.x & 63;
    if (wave >= N) return;
    const int node = wave;

    if constexpr (D == 128) {
        const float2* Gv = reinterpret_cast<const float2*>(G);
        float2 acc = Gv[(size_t)node * 64 + lane];          // self-loop
        const int beg = rowptr[node], end = rowptr[node + 1];
        int j = beg;
        for (; j + 4 <= end; j += 4) {
            int s0 = col[j], s1 = col[j + 1], s2 = col[j + 2], s3 = col[j + 3];
            float2 v0 = Gv[(size_t)s0 * 64 + lane];
            float2 v1 = Gv[(size_t)s1 * 64 + lane];
            float2 v2 = Gv[(size_t)s2 * 64 + lane];
            float2 v3 = Gv[(size_t)s3 * 64 + lane];
            acc.x += v0.x; acc.y += v0.y;
            acc.x += v1.x; acc.y += v1.y;
            acc.x += v2.x; acc.y += v2.y;
            acc.x += v3.x; acc.y += v3.y;
        }
        for (; j < end; ++j) {
            float2 v = Gv[(size_t)col[j] * 64 + lane];
            acc.x += v.x; acc.y += v.y;
        }
        float dv = dinv[node];
        float2 bb = reinterpret_cast<const float2*>(bias)[lane];
        float2 o;
        o.x = dv * acc.x + bb.x;
        o.y = dv * acc.y + bb.y;
        if constexpr (RELU) { o.x = fmaxf(o.x, 0.f); o.y = fmaxf(o.y, 0.f); }
        reinterpret_cast<float2*>(out)[(size_t)node * 64 + lane] = o;
    } else {  // D == 64
        float acc = G[(size_t)node * 64 + lane];            // self-loop
        const int beg = rowptr[node], end = rowptr[node + 1];
        int j = beg;
        for (; j + 4 <= end; j += 4) {
            int s0 = col[j], s1 = col[j + 1], s2 = col[j + 2], s3 = col[j + 3];
            float v0 = G[(size_t)s0 * 64 + lane];
            float v1 = G[(size_t)s1 * 64 + lane];
            float v2 = G[(size_t)s2 * 64 + lane];
            float v3 = G[(size_t)s3 * 64 + lane];
            acc += v0; acc += v1; acc += v2; acc += v3;
        }
        for (; j < end; ++j) acc += G[(size_t)col[j] * 64 + lane];
        float dv = dinv[node];
        float o = dv * acc + bias[lane];
        if constexpr (RELU) o = fmaxf(o, 0.f);
        out[(size_t)node * 64 + lane] = o;
    }
}

static inline size_t align256(size_t x) { return (x + 255) & ~size_t(255); }

extern "C" void kernel_launch(void* const* d_in, const int* in_sizes, int n_in,
                              void* d_out, int out_size, void* d_ws, size_t ws_size,
                              hipStream_t stream) {
    const float* e_prev = (const float*)d_in[0];
    const int*   eidx   = (const int*)d_in[1];
    const float* W1     = (const float*)d_in[2];
    const float* b1     = (const float*)d_in[3];
    const float* W2     = (const float*)d_in[4];
    const float* b2     = (const float*)d_in[5];

    const int dh   = in_sizes[3];            // 128
    const int din  = in_sizes[2] / dh;       // 128
    const int N    = in_sizes[0] / din;      // 50000
    const int E    = in_sizes[1] / 2;        // 800000
    (void)dh;

    const int* src = eidx;
    const int* dst = eidx + E;

    // workspace layout (~55 MB)
    char* ws = (char*)d_ws;
    size_t off = 0;
    int*   cnt    = (int*)(ws + off);   off = align256(off + (size_t)N * 4);        // degree, later fill cursor
    float* dinv   = (float*)(ws + off); off = align256(off + (size_t)N * 4);
    int*   rowptr = (int*)(ws + off);   off = align256(off + (size_t)(N + 1) * 4);
    int*   col    = (int*)(ws + off);   off = align256(off + (size_t)E * 4);
    float* bufA   = (float*)(ws + off); off = align256(off + (size_t)N * DIN * 4);
    float* bufB   = (float*)(ws + off); off = align256(off + (size_t)N * DIN * 4);
    (void)ws_size;

    float* outp = (float*)d_out;

    const int T = 256;
    const int gN = (N + T - 1) / T;
    const int gE = (E + T - 1) / T;
    const int gW = (N + 3) / 4;              // 4 waves per 256-thread block

    // ---- CSR build ----
    zero_int_k<<<gN, T, 0, stream>>>(cnt, N);
    count_deg_k<<<gE, T, 0, stream>>>(dst, cnt, E);
    dinv_k<<<gN, T, 0, stream>>>(cnt, dinv, N);
    scan_k<<<1, 1024, 0, stream>>>(cnt, rowptr, N);
    zero_int_k<<<gN, T, 0, stream>>>(cnt, N);                 // reuse as fill cursor
    fill_k<<<gE, T, 0, stream>>>(src, dst, rowptr, cnt, col, E);

    // ---- layer 1 ----
    gemm_scale_k<128><<<(N + 63) / 64, T, 0, stream>>>(e_prev, W1, dinv, bufA, N);
    gather_k<128, true><<<gW, T, 0, stream>>>(bufA, rowptr, col, dinv, b1, bufB, N);

    // ---- layer 2 ----
    gemm_scale_k<64><<<(N + 63) / 64, T, 0, stream>>>(bufB, W2, dinv, bufA, N);
    gather_k<64, false><<<gW, T, 0, stream>>>(bufA, rowptr, col, dinv, b2, outp, N);
}

// Round 8
// 339.915 us; speedup vs baseline: 6.5814x; 1.2087x over previous
//
#include <hip/hip_runtime.h>

// GCN 2-layer via CSR gather (no float atomics):
// out = dinv ⊙ (A · (dinv ⊙ (relu(dinv ⊙ (A · (dinv ⊙ (x@W1))) + b1) @ W2))) + b2
// A = adjacency (dst<-src) + I.  dinv[src] folded into G rows pre-aggregation,
// dinv[dst] applied in gather epilogue; self-loop = own G row.

constexpr int DIN = 128;

// ---- small utility kernels -------------------------------------------------
__global__ void zero_int_k(int* __restrict__ p, int n) {
    int i = blockIdx.x * 256 + threadIdx.x;
    if (i < n) p[i] = 0;
}

__global__ void count_deg_k(const int* __restrict__ dst, int* __restrict__ cnt, int e) {
    int i = blockIdx.x * 256 + threadIdx.x;
    if (i < e) atomicAdd(&cnt[dst[i]], 1);
}

__global__ void dinv_k(const int* __restrict__ cnt, float* __restrict__ dinv, int n) {
    int i = blockIdx.x * 256 + threadIdx.x;
    if (i < n) dinv[i] = rsqrtf((float)cnt[i] + 1.0f);   // +1 self-loop
}

// ---- hierarchical exclusive scan: rowptr[0..n] from cnt[0..n-1] ------------
// scan1: per-block (1024-elem tile) exclusive scan + block sums
__global__ __launch_bounds__(256) void scan1_k(const int* __restrict__ cnt,
                                               int* __restrict__ rowptr,
                                               int* __restrict__ bsum,
                                               int n_out, int n_cnt) {
    __shared__ int wsum[4];
    const int tid  = threadIdx.x;
    const int lane = tid & 63;
    const int wv   = tid >> 6;
    const int base = blockIdx.x * 1024 + tid * 4;

    int v0 = (base + 0 < n_cnt) ? cnt[base + 0] : 0;
    int v1 = (base + 1 < n_cnt) ? cnt[base + 1] : 0;
    int v2 = (base + 2 < n_cnt) ? cnt[base + 2] : 0;
    int v3 = (base + 3 < n_cnt) ? cnt[base + 3] : 0;
    int tsum = v0 + v1 + v2 + v3;

    // wave inclusive scan of tsum
    int incl = tsum;
    for (int d = 1; d < 64; d <<= 1) {
        int t = __shfl_up(incl, d, 64);
        if (lane >= d) incl += t;
    }
    if (lane == 63) wsum[wv] = incl;
    __syncthreads();
    int woff = 0;
    for (int w = 0; w < wv; ++w) woff += wsum[w];
    int excl = woff + incl - tsum;     // exclusive prefix for this thread's 4 elems

    int e0 = excl;
    int e1 = e0 + v0;
    int e2 = e1 + v1;
    int e3 = e2 + v2;
    if (base + 0 < n_out) rowptr[base + 0] = e0;
    if (base + 1 < n_out) rowptr[base + 1] = e1;
    if (base + 2 < n_out) rowptr[base + 2] = e2;
    if (base + 3 < n_out) rowptr[base + 3] = e3;

    if (tid == 255) bsum[blockIdx.x] = woff + incl;   // block total
}

// scan2: single block, exclusive scan of nb (<=1024) block sums in place
__global__ __launch_bounds__(1024) void scan2_k(int* __restrict__ bsum, int nb) {
    __shared__ int sh[1024];
    const int t = threadIdx.x;
    int v = (t < nb) ? bsum[t] : 0;
    sh[t] = v;
    __syncthreads();
    for (int d = 1; d < 1024; d <<= 1) {
        int x = (t >= d) ? sh[t - d] : 0;
        __syncthreads();
        sh[t] += x;
        __syncthreads();
    }
    if (t < nb) bsum[t] = sh[t] - v;   // exclusive
}

// scan3: add block offsets
__global__ void scan3_k(int* __restrict__ rowptr, const int* __restrict__ bsum, int n_out) {
    int i = blockIdx.x * 256 + threadIdx.x;
    if (i < n_out) rowptr[i] += bsum[i >> 10];
}

__global__ void fill_k(const int* __restrict__ src, const int* __restrict__ dst,
                       const int* __restrict__ rowptr, int* __restrict__ cur,
                       int* __restrict__ col, int e) {
    int i = blockIdx.x * 256 + threadIdx.x;
    if (i >= e) return;
    int d = dst[i];
    int pos = rowptr[d] + atomicAdd(&cur[d], 1);
    col[pos] = src[i];
}

// ---- fused GEMM + row scale:  G = dinv[:,None] * (X @ W) -------------------
template <int DOUT>
__global__ __launch_bounds__(256) void gemm_scale_k(
    const float* __restrict__ X, const float* __restrict__ W,
    const float* __restrict__ dinv, float* __restrict__ G, int N)
{
    constexpr int TM = 64;
    constexpr int C4 = DOUT / 4;
    constexpr int GROUPS = 256 / C4;
    constexpr int RPT = TM / GROUPS;

    __shared__ float sW[DIN * DOUT];
    __shared__ float sX[TM * DIN];

    const int tid  = threadIdx.x;
    const int base = blockIdx.x * TM;

    for (int idx = tid; idx < DIN * DOUT / 4; idx += 256)
        reinterpret_cast<float4*>(sW)[idx] = reinterpret_cast<const float4*>(W)[idx];

    for (int idx = tid; idx < TM * DIN / 4; idx += 256) {
        int row  = idx / (DIN / 4);
        int grow = base + row;
        float4 v = make_float4(0.f, 0.f, 0.f, 0.f);
        if (grow < N)
            v = reinterpret_cast<const float4*>(X)[(size_t)grow * (DIN / 4) + (idx % (DIN / 4))];
        reinterpret_cast<float4*>(sX)[idx] = v;
    }
    __syncthreads();

    const int cq = tid % C4;
    const int rg = tid / C4;

    float4 acc[RPT];
#pragma unroll
    for (int r = 0; r < RPT; ++r) acc[r] = make_float4(0.f, 0.f, 0.f, 0.f);

#pragma unroll 4
    for (int k = 0; k < DIN; ++k) {
        float4 w = reinterpret_cast<const float4*>(sW)[k * C4 + cq];
#pragma unroll
        for (int r = 0; r < RPT; ++r) {
            float xv = sX[(rg + r * GROUPS) * DIN + k];
            acc[r].x = fmaf(xv, w.x, acc[r].x);
            acc[r].y = fmaf(xv, w.y, acc[r].y);
            acc[r].z = fmaf(xv, w.z, acc[r].z);
            acc[r].w = fmaf(xv, w.w, acc[r].w);
        }
    }

#pragma unroll
    for (int r = 0; r < RPT; ++r) {
        int row = base + rg + r * GROUPS;
        if (row < N) {
            float dv = dinv[row];
            float4 o = make_float4(acc[r].x * dv, acc[r].y * dv, acc[r].z * dv, acc[r].w * dv);
            reinterpret_cast<float4*>(G)[(size_t)row * C4 + cq] = o;
        }
    }
}

// ---- gather: one wave per node --------------------------------------------
// out[i] = op( dinv[i] * (G[i] + sum_{j in CSR row i} G[col[j]]) + bias )
template <int D, bool RELU>
__global__ __launch_bounds__(256) void gather_k(
    const float* __restrict__ G, const int* __restrict__ rowptr,
    const int* __restrict__ col, const float* __restrict__ dinv,
    const float* __restrict__ bias, float* __restrict__ out, int N)
{
    const int wave = (blockIdx.x * 256 + threadIdx.x) >> 6;
    const int lane = threadIdx.x & 63;
    if (wave >= N) return;
    const int node = wave;

    if constexpr (D == 128) {
        const float2* Gv = reinterpret_cast<const float2*>(G);
        float2 acc = Gv[(size_t)node * 64 + lane];          // self-loop
        const int beg = rowptr[node], end = rowptr[node + 1];
        int j = beg;
        for (; j + 4 <= end; j += 4) {
            int s0 = col[j], s1 = col[j + 1], s2 = col[j + 2], s3 = col[j + 3];
            float2 v0 = Gv[(size_t)s0 * 64 + lane];
            float2 v1 = Gv[(size_t)s1 * 64 + lane];
            float2 v2 = Gv[(size_t)s2 * 64 + lane];
            float2 v3 = Gv[(size_t)s3 * 64 + lane];
            acc.x += v0.x; acc.y += v0.y;
            acc.x += v1.x; acc.y += v1.y;
            acc.x += v2.x; acc.y += v2.y;
            acc.x += v3.x; acc.y += v3.y;
        }
        for (; j < end; ++j) {
            float2 v = Gv[(size_t)col[j] * 64 + lane];
            acc.x += v.x; acc.y += v.y;
        }
        float dv = dinv[node];
        float2 bb = reinterpret_cast<const float2*>(bias)[lane];
        float2 o;
        o.x = dv * acc.x + bb.x;
        o.y = dv * acc.y + bb.y;
        if constexpr (RELU) { o.x = fmaxf(o.x, 0.f); o.y = fmaxf(o.y, 0.f); }
        reinterpret_cast<float2*>(out)[(size_t)node * 64 + lane] = o;
    } else {  // D == 64
        float acc = G[(size_t)node * 64 + lane];            // self-loop
        const int beg = rowptr[node], end = rowptr[node + 1];
        int j = beg;
        for (; j + 4 <= end; j += 4) {
            int s0 = col[j], s1 = col[j + 1], s2 = col[j + 2], s3 = col[j + 3];
            float v0 = G[(size_t)s0 * 64 + lane];
            float v1 = G[(size_t)s1 * 64 + lane];
            float v2 = G[(size_t)s2 * 64 + lane];
            float v3 = G[(size_t)s3 * 64 + lane];
            acc += v0; acc += v1; acc += v2; acc += v3;
        }
        for (; j < end; ++j) acc += G[(size_t)col[j] * 64 + lane];
        float dv = dinv[node];
        float o = dv * acc + bias[lane];
        if constexpr (RELU) o = fmaxf(o, 0.f);
        out[(size_t)node * 64 + lane] = o;
    }
}

static inline size_t align256(size_t x) { return (x + 255) & ~size_t(255); }

extern "C" void kernel_launch(void* const* d_in, const int* in_sizes, int n_in,
                              void* d_out, int out_size, void* d_ws, size_t ws_size,
                              hipStream_t stream) {
    const float* e_prev = (const float*)d_in[0];
    const int*   eidx   = (const int*)d_in[1];
    const float* W1     = (const float*)d_in[2];
    const float* b1     = (const float*)d_in[3];
    const float* W2     = (const float*)d_in[4];
    const float* b2     = (const float*)d_in[5];

    const int dh   = in_sizes[3];            // 128
    const int din  = in_sizes[2] / dh;       // 128
    const int N    = in_sizes[0] / din;      // 50000
    const int E    = in_sizes[1] / 2;        // 800000
    (void)dh;

    const int* src = eidx;
    const int* dst = eidx + E;

    // workspace layout (~55 MB)
    char* ws = (char*)d_ws;
    size_t off = 0;
    int*   cnt    = (int*)(ws + off);   off = align256(off + (size_t)N * 4);
    float* dinv   = (float*)(ws + off); off = align256(off + (size_t)N * 4);
    int*   rowptr = (int*)(ws + off);   off = align256(off + (size_t)(N + 1) * 4);
    int*   bsum   = (int*)(ws + off);   off = align256(off + (size_t)1024 * 4);
    int*   col    = (int*)(ws + off);   off = align256(off + (size_t)E * 4);
    float* bufA   = (float*)(ws + off); off = align256(off + (size_t)N * DIN * 4);
    float* bufB   = (float*)(ws + off); off = align256(off + (size_t)N * DIN * 4);
    (void)ws_size;

    float* outp = (float*)d_out;

    const int T = 256;
    const int gN = (N + T - 1) / T;
    const int gE = (E + T - 1) / T;
    const int gW = (N + 3) / 4;              // 4 waves per 256-thread block
    const int n_out = N + 1;
    const int nb = (n_out + 1023) / 1024;    // scan tiles

    // ---- CSR build ----
    zero_int_k<<<gN, T, 0, stream>>>(cnt, N);
    count_deg_k<<<gE, T, 0, stream>>>(dst, cnt, E);
    dinv_k<<<gN, T, 0, stream>>>(cnt, dinv, N);
    scan1_k<<<nb, T, 0, stream>>>(cnt, rowptr, bsum, n_out, N);
    scan2_k<<<1, 1024, 0, stream>>>(bsum, nb);
    scan3_k<<<(n_out + T - 1) / T, T, 0, stream>>>(rowptr, bsum, n_out);
    zero_int_k<<<gN, T, 0, stream>>>(cnt, N);                 // reuse as fill cursor
    fill_k<<<gE, T, 0, stream>>>(src, dst, rowptr, cnt, col, E);

    // ---- layer 1 ----
    gemm_scale_k<128><<<(N + 63) / 64, T, 0, stream>>>(e_prev, W1, dinv, bufA, N);
    gather_k<128, true><<<gW, T, 0, stream>>>(bufA, rowptr, col, dinv, b1, bufB, N);

    // ---- layer 2 ----
    gemm_scale_k<64><<<(N + 63) / 64, T, 0, stream>>>(bufB, W2, dinv, bufA, N);
    gather_k<64, false><<<gW, T, 0, stream>>>(bufA, rowptr, col, dinv, b2, outp, N);
}

// Round 9
// 316.364 us; speedup vs baseline: 7.0713x; 1.0744x over previous
//
#include <hip/hip_runtime.h>

// GCN 2-layer via CSR gather (no float atomics):
// out = dinv ⊙ (A · (dinv ⊙ (relu(dinv ⊙ (A · (dinv ⊙ (x@W1))) + b1) @ W2))) + b2
// A = adjacency (dst<-src) + I.  dinv[src] folded into G rows pre-aggregation,
// dinv[dst] applied in gather epilogue; self-loop = own G row.

constexpr int DIN = 128;

// ---- small utility kernels -------------------------------------------------
__global__ void zero_int_k(int* __restrict__ p, int n) {
    int i = blockIdx.x * 256 + threadIdx.x;
    if (i < n) p[i] = 0;
}

__global__ void count_deg_k(const int* __restrict__ dst, int* __restrict__ cnt, int e) {
    int i = blockIdx.x * 256 + threadIdx.x;
    if (i < e) atomicAdd(&cnt[dst[i]], 1);
}

__global__ void dinv_k(const int* __restrict__ cnt, float* __restrict__ dinv, int n) {
    int i = blockIdx.x * 256 + threadIdx.x;
    if (i < n) dinv[i] = rsqrtf((float)cnt[i] + 1.0f);   // +1 self-loop
}

// ---- hierarchical exclusive scan: rowptr[0..n] from cnt[0..n-1] ------------
__global__ __launch_bounds__(256) void scan1_k(const int* __restrict__ cnt,
                                               int* __restrict__ rowptr,
                                               int* __restrict__ bsum,
                                               int n_out, int n_cnt) {
    __shared__ int wsum[4];
    const int tid  = threadIdx.x;
    const int lane = tid & 63;
    const int wv   = tid >> 6;
    const int base = blockIdx.x * 1024 + tid * 4;

    int v0 = (base + 0 < n_cnt) ? cnt[base + 0] : 0;
    int v1 = (base + 1 < n_cnt) ? cnt[base + 1] : 0;
    int v2 = (base + 2 < n_cnt) ? cnt[base + 2] : 0;
    int v3 = (base + 3 < n_cnt) ? cnt[base + 3] : 0;
    int tsum = v0 + v1 + v2 + v3;

    int incl = tsum;
    for (int d = 1; d < 64; d <<= 1) {
        int t = __shfl_up(incl, d, 64);
        if (lane >= d) incl += t;
    }
    if (lane == 63) wsum[wv] = incl;
    __syncthreads();
    int woff = 0;
    for (int w = 0; w < wv; ++w) woff += wsum[w];
    int excl = woff + incl - tsum;

    int e0 = excl;
    int e1 = e0 + v0;
    int e2 = e1 + v1;
    int e3 = e2 + v2;
    if (base + 0 < n_out) rowptr[base + 0] = e0;
    if (base + 1 < n_out) rowptr[base + 1] = e1;
    if (base + 2 < n_out) rowptr[base + 2] = e2;
    if (base + 3 < n_out) rowptr[base + 3] = e3;

    if (tid == 255) bsum[blockIdx.x] = woff + incl;
}

__global__ __launch_bounds__(1024) void scan2_k(int* __restrict__ bsum, int nb) {
    __shared__ int sh[1024];
    const int t = threadIdx.x;
    int v = (t < nb) ? bsum[t] : 0;
    sh[t] = v;
    __syncthreads();
    for (int d = 1; d < 1024; d <<= 1) {
        int x = (t >= d) ? sh[t - d] : 0;
        __syncthreads();
        sh[t] += x;
        __syncthreads();
    }
    if (t < nb) bsum[t] = sh[t] - v;
}

__global__ void scan3_k(int* __restrict__ rowptr, const int* __restrict__ bsum, int n_out) {
    int i = blockIdx.x * 256 + threadIdx.x;
    if (i < n_out) rowptr[i] += bsum[i >> 10];
}

__global__ void fill_k(const int* __restrict__ src, const int* __restrict__ dst,
                       const int* __restrict__ rowptr, int* __restrict__ cur,
                       int* __restrict__ col, int e) {
    int i = blockIdx.x * 256 + threadIdx.x;
    if (i >= e) return;
    int d = dst[i];
    int pos = rowptr[d] + atomicAdd(&cur[d], 1);
    col[pos] = src[i];
}

// ---- fused GEMM + row scale:  G = dinv[:,None] * (X @ W) -------------------
// W read directly from global (L1/L2-resident, broadcast across row-group);
// only X staged in LDS (32 KB) -> 4-5 blocks/CU instead of 1.
template <int DOUT>
__global__ __launch_bounds__(256, 4) void gemm_scale_k(
    const float* __restrict__ X, const float* __restrict__ W,
    const float* __restrict__ dinv, float* __restrict__ G, int N)
{
    constexpr int TM = 64;
    constexpr int C4 = DOUT / 4;        // float4 cols (32 / 16)
    constexpr int GROUPS = 256 / C4;    // row groups (8 / 16)
    constexpr int RPT = TM / GROUPS;    // rows per thread (8 / 4)

    __shared__ float sX[TM * DIN];      // 32 KB

    const int tid  = threadIdx.x;
    const int base = blockIdx.x * TM;
    const float4* Wv = reinterpret_cast<const float4*>(W);

    for (int idx = tid; idx < TM * DIN / 4; idx += 256) {
        int row  = idx / (DIN / 4);
        int grow = base + row;
        float4 v = make_float4(0.f, 0.f, 0.f, 0.f);
        if (grow < N)
            v = reinterpret_cast<const float4*>(X)[(size_t)grow * (DIN / 4) + (idx % (DIN / 4))];
        reinterpret_cast<float4*>(sX)[idx] = v;
    }
    __syncthreads();

    const int cq = tid % C4;
    const int rg = tid / C4;

    float4 acc[RPT];
#pragma unroll
    for (int r = 0; r < RPT; ++r) acc[r] = make_float4(0.f, 0.f, 0.f, 0.f);

#pragma unroll 4
    for (int k = 0; k < DIN; ++k) {
        float4 w = Wv[k * C4 + cq];
#pragma unroll
        for (int r = 0; r < RPT; ++r) {
            float xv = sX[(rg + r * GROUPS) * DIN + k];
            acc[r].x = fmaf(xv, w.x, acc[r].x);
            acc[r].y = fmaf(xv, w.y, acc[r].y);
            acc[r].z = fmaf(xv, w.z, acc[r].z);
            acc[r].w = fmaf(xv, w.w, acc[r].w);
        }
    }

#pragma unroll
    for (int r = 0; r < RPT; ++r) {
        int row = base + rg + r * GROUPS;
        if (row < N) {
            float dv = dinv[row];
            float4 o = make_float4(acc[r].x * dv, acc[r].y * dv, acc[r].z * dv, acc[r].w * dv);
            reinterpret_cast<float4*>(G)[(size_t)row * C4 + cq] = o;
        }
    }
}

// ---- gather: one wave per node --------------------------------------------
// out[i] = op( dinv[i] * (G[i] + sum_{j in CSR row i} G[col[j]]) + bias )
template <int D, bool RELU>
__global__ __launch_bounds__(256) void gather_k(
    const float* __restrict__ G, const int* __restrict__ rowptr,
    const int* __restrict__ col, const float* __restrict__ dinv,
    const float* __restrict__ bias, float* __restrict__ out, int N)
{
    const int wave = (blockIdx.x * 256 + threadIdx.x) >> 6;
    const int lane = threadIdx.x & 63;
    if (wave >= N) return;
    const int node = wave;

    if constexpr (D == 128) {
        const float2* Gv = reinterpret_cast<const float2*>(G);
        float2 acc = Gv[(size_t)node * 64 + lane];          // self-loop
        const int beg = rowptr[node], end = rowptr[node + 1];
        int j = beg;
        for (; j + 4 <= end; j += 4) {
            int s0 = col[j], s1 = col[j + 1], s2 = col[j + 2], s3 = col[j + 3];
            float2 v0 = Gv[(size_t)s0 * 64 + lane];
            float2 v1 = Gv[(size_t)s1 * 64 + lane];
            float2 v2 = Gv[(size_t)s2 * 64 + lane];
            float2 v3 = Gv[(size_t)s3 * 64 + lane];
            acc.x += v0.x; acc.y += v0.y;
            acc.x += v1.x; acc.y += v1.y;
            acc.x += v2.x; acc.y += v2.y;
            acc.x += v3.x; acc.y += v3.y;
        }
        for (; j < end; ++j) {
            float2 v = Gv[(size_t)col[j] * 64 + lane];
            acc.x += v.x; acc.y += v.y;
        }
        float dv = dinv[node];
        float2 bb = reinterpret_cast<const float2*>(bias)[lane];
        float2 o;
        o.x = dv * acc.x + bb.x;
        o.y = dv * acc.y + bb.y;
        if constexpr (RELU) { o.x = fmaxf(o.x, 0.f); o.y = fmaxf(o.y, 0.f); }
        reinterpret_cast<float2*>(out)[(size_t)node * 64 + lane] = o;
    } else {  // D == 64
        float acc = G[(size_t)node * 64 + lane];            // self-loop
        const int beg = rowptr[node], end = rowptr[node + 1];
        int j = beg;
        for (; j + 4 <= end; j += 4) {
            int s0 = col[j], s1 = col[j + 1], s2 = col[j + 2], s3 = col[j + 3];
            float v0 = G[(size_t)s0 * 64 + lane];
            float v1 = G[(size_t)s1 * 64 + lane];
            float v2 = G[(size_t)s2 * 64 + lane];
            float v3 = G[(size_t)s3 * 64 + lane];
            acc += v0; acc += v1; acc += v2; acc += v3;
        }
        for (; j < end; ++j) acc += G[(size_t)col[j] * 64 + lane];
        float dv = dinv[node];
        float o = dv * acc + bias[lane];
        if constexpr (RELU) o = fmaxf(o, 0.f);
        out[(size_t)node * 64 + lane] = o;
    }
}

static inline size_t align256(size_t x) { return (x + 255) & ~size_t(255); }

extern "C" void kernel_launch(void* const* d_in, const int* in_sizes, int n_in,
                              void* d_out, int out_size, void* d_ws, size_t ws_size,
                              hipStream_t stream) {
    const float* e_prev = (const float*)d_in[0];
    const int*   eidx   = (const int*)d_in[1];
    const float* W1     = (const float*)d_in[2];
    const float* b1     = (const float*)d_in[3];
    const float* W2     = (const float*)d_in[4];
    const float* b2     = (const float*)d_in[5];

    const int dh   = in_sizes[3];            // 128
    const int din  = in_sizes[2] / dh;       // 128
    const int N    = in_sizes[0] / din;      // 50000
    const int E    = in_sizes[1] / 2;        // 800000
    (void)dh;

    const int* src = eidx;
    const int* dst = eidx + E;

    // workspace layout (~55 MB)
    char* ws = (char*)d_ws;
    size_t off = 0;
    int*   cnt    = (int*)(ws + off);   off = align256(off + (size_t)N * 4);
    float* dinv   = (float*)(ws + off); off = align256(off + (size_t)N * 4);
    int*   rowptr = (int*)(ws + off);   off = align256(off + (size_t)(N + 1) * 4);
    int*   bsum   = (int*)(ws + off);   off = align256(off + (size_t)1024 * 4);
    int*   col    = (int*)(ws + off);   off = align256(off + (size_t)E * 4);
    float* bufA   = (float*)(ws + off); off = align256(off + (size_t)N * DIN * 4);
    float* bufB   = (float*)(ws + off); off = align256(off + (size_t)N * DIN * 4);
    (void)ws_size;

    float* outp = (float*)d_out;

    const int T = 256;
    const int gN = (N + T - 1) / T;
    const int gE = (E + T - 1) / T;
    const int gW = (N + 3) / 4;              // 4 waves per 256-thread block
    const int n_out = N + 1;
    const int nb = (n_out + 1023) / 1024;    // scan tiles

    // ---- CSR build ----
    zero_int_k<<<gN, T, 0, stream>>>(cnt, N);
    count_deg_k<<<gE, T, 0, stream>>>(dst, cnt, E);
    dinv_k<<<gN, T, 0, stream>>>(cnt, dinv, N);
    scan1_k<<<nb, T, 0, stream>>>(cnt, rowptr, bsum, n_out, N);
    scan2_k<<<1, 1024, 0, stream>>>(bsum, nb);
    scan3_k<<<(n_out + T - 1) / T, T, 0, stream>>>(rowptr, bsum, n_out);
    zero_int_k<<<gN, T, 0, stream>>>(cnt, N);                 // reuse as fill cursor
    fill_k<<<gE, T, 0, stream>>>(src, dst, rowptr, cnt, col, E);

    // ---- layer 1 ----
    gemm_scale_k<128><<<(N + 63) / 64, T, 0, stream>>>(e_prev, W1, dinv, bufA, N);
    gather_k<128, true><<<gW, T, 0, stream>>>(bufA, rowptr, col, dinv, b1, bufB, N);

    // ---- layer 2 ----
    gemm_scale_k<64><<<(N + 63) / 64, T, 0, stream>>>(bufB, W2, dinv, bufA, N);
    gather_k<64, false><<<gW, T, 0, stream>>>(bufA, rowptr, col, dinv, b2, outp, N);
}

// Round 10
// 312.132 us; speedup vs baseline: 7.1672x; 1.0136x over previous
//
#include <hip/hip_runtime.h>

// GCN 2-layer via CSR gather (no float atomics):
// out = dinv ⊙ (A · (dinv ⊙ (relu(dinv ⊙ (A · (dinv ⊙ (x@W1))) + b1) @ W2))) + b2
// A = adjacency (dst<-src) + I.  dinv[src] folded into G rows pre-aggregation,
// dinv[dst] applied in gather epilogue; self-loop = own G row.

constexpr int DIN = 128;

// ---- small utility kernels -------------------------------------------------
__global__ void zero_int_k(int* __restrict__ p, int n) {
    int i = blockIdx.x * 256 + threadIdx.x;
    if (i < n) p[i] = 0;
}

__global__ void count_deg_k(const int* __restrict__ dst, int* __restrict__ cnt, int e) {
    int i = blockIdx.x * 256 + threadIdx.x;
    if (i < e) atomicAdd(&cnt[dst[i]], 1);
}

__global__ void dinv_k(const int* __restrict__ cnt, float* __restrict__ dinv, int n) {
    int i = blockIdx.x * 256 + threadIdx.x;
    if (i < n) dinv[i] = rsqrtf((float)cnt[i] + 1.0f);   // +1 self-loop
}

// ---- hierarchical exclusive scan: rowptr[0..n] from cnt[0..n-1] ------------
__global__ __launch_bounds__(256) void scan1_k(const int* __restrict__ cnt,
                                               int* __restrict__ rowptr,
                                               int* __restrict__ bsum,
                                               int n_out, int n_cnt) {
    __shared__ int wsum[4];
    const int tid  = threadIdx.x;
    const int lane = tid & 63;
    const int wv   = tid >> 6;
    const int base = blockIdx.x * 1024 + tid * 4;

    int v0 = (base + 0 < n_cnt) ? cnt[base + 0] : 0;
    int v1 = (base + 1 < n_cnt) ? cnt[base + 1] : 0;
    int v2 = (base + 2 < n_cnt) ? cnt[base + 2] : 0;
    int v3 = (base + 3 < n_cnt) ? cnt[base + 3] : 0;
    int tsum = v0 + v1 + v2 + v3;

    int incl = tsum;
    for (int d = 1; d < 64; d <<= 1) {
        int t = __shfl_up(incl, d, 64);
        if (lane >= d) incl += t;
    }
    if (lane == 63) wsum[wv] = incl;
    __syncthreads();
    int woff = 0;
    for (int w = 0; w < wv; ++w) woff += wsum[w];
    int excl = woff + incl - tsum;

    int e0 = excl;
    int e1 = e0 + v0;
    int e2 = e1 + v1;
    int e3 = e2 + v2;
    if (base + 0 < n_out) rowptr[base + 0] = e0;
    if (base + 1 < n_out) rowptr[base + 1] = e1;
    if (base + 2 < n_out) rowptr[base + 2] = e2;
    if (base + 3 < n_out) rowptr[base + 3] = e3;

    if (tid == 255) bsum[blockIdx.x] = woff + incl;
}

__global__ __launch_bounds__(1024) void scan2_k(int* __restrict__ bsum, int nb) {
    __shared__ int sh[1024];
    const int t = threadIdx.x;
    int v = (t < nb) ? bsum[t] : 0;
    sh[t] = v;
    __syncthreads();
    for (int d = 1; d < 1024; d <<= 1) {
        int x = (t >= d) ? sh[t - d] : 0;
        __syncthreads();
        sh[t] += x;
        __syncthreads();
    }
    if (t < nb) bsum[t] = sh[t] - v;
}

__global__ void scan3_k(int* __restrict__ rowptr, const int* __restrict__ bsum, int n_out) {
    int i = blockIdx.x * 256 + threadIdx.x;
    if (i < n_out) rowptr[i] += bsum[i >> 10];
}

__global__ void fill_k(const int* __restrict__ src, const int* __restrict__ dst,
                       const int* __restrict__ rowptr, int* __restrict__ cur,
                       int* __restrict__ col, int e) {
    int i = blockIdx.x * 256 + threadIdx.x;
    if (i >= e) return;
    int d = dst[i];
    int pos = rowptr[d] + atomicAdd(&cur[d], 1);
    col[pos] = src[i];
}

// ---- fused GEMM + row scale:  G = dinv[:,None] * (X @ W) -------------------
// W read directly from global (L1/L2-resident, broadcast across row-group);
// only X staged in LDS (32 KB) -> 4-5 blocks/CU.
template <int DOUT>
__global__ __launch_bounds__(256, 4) void gemm_scale_k(
    const float* __restrict__ X, const float* __restrict__ W,
    const float* __restrict__ dinv, float* __restrict__ G, int N)
{
    constexpr int TM = 64;
    constexpr int C4 = DOUT / 4;        // float4 cols (32 / 16)
    constexpr int GROUPS = 256 / C4;    // row groups (8 / 16)
    constexpr int RPT = TM / GROUPS;    // rows per thread (8 / 4)

    __shared__ float sX[TM * DIN];      // 32 KB

    const int tid  = threadIdx.x;
    const int base = blockIdx.x * TM;
    const float4* Wv = reinterpret_cast<const float4*>(W);

    for (int idx = tid; idx < TM * DIN / 4; idx += 256) {
        int row  = idx / (DIN / 4);
        int grow = base + row;
        float4 v = make_float4(0.f, 0.f, 0.f, 0.f);
        if (grow < N)
            v = reinterpret_cast<const float4*>(X)[(size_t)grow * (DIN / 4) + (idx % (DIN / 4))];
        reinterpret_cast<float4*>(sX)[idx] = v;
    }
    __syncthreads();

    const int cq = tid % C4;
    const int rg = tid / C4;

    float4 acc[RPT];
#pragma unroll
    for (int r = 0; r < RPT; ++r) acc[r] = make_float4(0.f, 0.f, 0.f, 0.f);

#pragma unroll 4
    for (int k = 0; k < DIN; ++k) {
        float4 w = Wv[k * C4 + cq];
#pragma unroll
        for (int r = 0; r < RPT; ++r) {
            float xv = sX[(rg + r * GROUPS) * DIN + k];
            acc[r].x = fmaf(xv, w.x, acc[r].x);
            acc[r].y = fmaf(xv, w.y, acc[r].y);
            acc[r].z = fmaf(xv, w.z, acc[r].z);
            acc[r].w = fmaf(xv, w.w, acc[r].w);
        }
    }

#pragma unroll
    for (int r = 0; r < RPT; ++r) {
        int row = base + rg + r * GROUPS;
        if (row < N) {
            float dv = dinv[row];
            float4 o = make_float4(acc[r].x * dv, acc[r].y * dv, acc[r].z * dv, acc[r].w * dv);
            reinterpret_cast<float4*>(G)[(size_t)row * C4 + cq] = o;
        }
    }
}

// ---- gather: one wave per node, slot-parallel edges ------------------------
// Wave split into NS = 64/(D/4) slots; each slot handles a different edge,
// each lane loads float4 (16 B). Final shfl_xor tree combines slots.
// out[i] = op( dinv[i] * (G[i] + sum_{j in CSR row i} G[col[j]]) + bias )
template <int D, bool RELU>
__global__ __launch_bounds__(256) void gather_k(
    const float* __restrict__ G, const int* __restrict__ rowptr,
    const int* __restrict__ col, const float* __restrict__ dinv,
    const float* __restrict__ bias, float* __restrict__ out, int N)
{
    constexpr int Q  = D / 4;    // float4 per row: 32 (D=128) / 16 (D=64)
    constexpr int NS = 64 / Q;   // edge slots per wave: 2 / 4

    const int wave = (blockIdx.x * 256 + threadIdx.x) >> 6;
    const int lane = threadIdx.x & 63;
    if (wave >= N) return;
    const int node = wave;
    const int q    = lane % Q;
    const int slot = lane / Q;

    const float4* G4 = reinterpret_cast<const float4*>(G);

    float4 acc = make_float4(0.f, 0.f, 0.f, 0.f);
    if (slot == 0) acc = G4[(size_t)node * Q + q];          // self-loop
    const int beg = rowptr[node], end = rowptr[node + 1];
    int j = beg;

    // 4*NS edges per unrolled block (8 / 16): 4 float4 loads in flight/lane
    for (; j + 4 * NS <= end; j += 4 * NS) {
        int s0 = col[j + 0 * NS + slot];
        int s1 = col[j + 1 * NS + slot];
        int s2 = col[j + 2 * NS + slot];
        int s3 = col[j + 3 * NS + slot];
        float4 v0 = G4[(size_t)s0 * Q + q];
        float4 v1 = G4[(size_t)s1 * Q + q];
        float4 v2 = G4[(size_t)s2 * Q + q];
        float4 v3 = G4[(size_t)s3 * Q + q];
        acc.x += v0.x; acc.y += v0.y; acc.z += v0.z; acc.w += v0.w;
        acc.x += v1.x; acc.y += v1.y; acc.z += v1.z; acc.w += v1.w;
        acc.x += v2.x; acc.y += v2.y; acc.z += v2.z; acc.w += v2.w;
        acc.x += v3.x; acc.y += v3.y; acc.z += v3.z; acc.w += v3.w;
    }
    for (; j + NS <= end; j += NS) {
        int s = col[j + slot];
        float4 v = G4[(size_t)s * Q + q];
        acc.x += v.x; acc.y += v.y; acc.z += v.z; acc.w += v.w;
    }
    {
        int rem = end - j;
        if (slot < rem) {
            int s = col[j + slot];
            float4 v = G4[(size_t)s * Q + q];
            acc.x += v.x; acc.y += v.y; acc.z += v.z; acc.w += v.w;
        }
    }

    // combine slots (lanes q, q+Q, q+2Q, ... hold partial sums of same cols)
#pragma unroll
    for (int d = Q; d < 64; d <<= 1) {
        acc.x += __shfl_xor(acc.x, d, 64);
        acc.y += __shfl_xor(acc.y, d, 64);
        acc.z += __shfl_xor(acc.z, d, 64);
        acc.w += __shfl_xor(acc.w, d, 64);
    }

    if (lane < Q) {
        float dv = dinv[node];
        float4 bb = reinterpret_cast<const float4*>(bias)[q];
        float4 o;
        o.x = dv * acc.x + bb.x;
        o.y = dv * acc.y + bb.y;
        o.z = dv * acc.z + bb.z;
        o.w = dv * acc.w + bb.w;
        if constexpr (RELU) {
            o.x = fmaxf(o.x, 0.f); o.y = fmaxf(o.y, 0.f);
            o.z = fmaxf(o.z, 0.f); o.w = fmaxf(o.w, 0.f);
        }
        reinterpret_cast<float4*>(out)[(size_t)node * Q + q] = o;
    }
}

static inline size_t align256(size_t x) { return (x + 255) & ~size_t(255); }

extern "C" void kernel_launch(void* const* d_in, const int* in_sizes, int n_in,
                              void* d_out, int out_size, void* d_ws, size_t ws_size,
                              hipStream_t stream) {
    const float* e_prev = (const float*)d_in[0];
    const int*   eidx   = (const int*)d_in[1];
    const float* W1     = (const float*)d_in[2];
    const float* b1     = (const float*)d_in[3];
    const float* W2     = (const float*)d_in[4];
    const float* b2     = (const float*)d_in[5];

    const int dh   = in_sizes[3];            // 128
    const int din  = in_sizes[2] / dh;       // 128
    const int N    = in_sizes[0] / din;      // 50000
    const int E    = in_sizes[1] / 2;        // 800000
    (void)dh;

    const int* src = eidx;
    const int* dst = eidx + E;

    // workspace layout (~55 MB)
    char* ws = (char*)d_ws;
    size_t off = 0;
    int*   cnt    = (int*)(ws + off);   off = align256(off + (size_t)N * 4);
    float* dinv   = (float*)(ws + off); off = align256(off + (size_t)N * 4);
    int*   rowptr = (int*)(ws + off);   off = align256(off + (size_t)(N + 1) * 4);
    int*   bsum   = (int*)(ws + off);   off = align256(off + (size_t)1024 * 4);
    int*   col    = (int*)(ws + off);   off = align256(off + (size_t)E * 4);
    float* bufA   = (float*)(ws + off); off = align256(off + (size_t)N * DIN * 4);
    float* bufB   = (float*)(ws + off); off = align256(off + (size_t)N * DIN * 4);
    (void)ws_size;

    float* outp = (float*)d_out;

    const int T = 256;
    const int gN = (N + T - 1) / T;
    const int gE = (E + T - 1) / T;
    const int gW = (N + 3) / 4;              // 4 waves per 256-thread block
    const int n_out = N + 1;
    const int nb = (n_out + 1023) / 1024;    // scan tiles

    // ---- CSR build ----
    zero_int_k<<<gN, T, 0, stream>>>(cnt, N);
    count_deg_k<<<gE, T, 0, stream>>>(dst, cnt, E);
    dinv_k<<<gN, T, 0, stream>>>(cnt, dinv, N);
    scan1_k<<<nb, T, 0, stream>>>(cnt, rowptr, bsum, n_out, N);
    scan2_k<<<1, 1024, 0, stream>>>(bsum, nb);
    scan3_k<<<(n_out + T - 1) / T, T, 0, stream>>>(rowptr, bsum, n_out);
    zero_int_k<<<gN, T, 0, stream>>>(cnt, N);                 // reuse as fill cursor
    fill_k<<<gE, T, 0, stream>>>(src, dst, rowptr, cnt, col, E);

    // ---- layer 1 ----
    gemm_scale_k<128><<<(N + 63) / 64, T, 0, stream>>>(e_prev, W1, dinv, bufA, N);
    gather_k<128, true><<<gW, T, 0, stream>>>(bufA, rowptr, col, dinv, b1, bufB, N);

    // ---- layer 2 ----
    gemm_scale_k<64><<<(N + 63) / 64, T, 0, stream>>>(bufB, W2, dinv, bufA, N);
    gather_k<64, false><<<gW, T, 0, stream>>>(bufA, rowptr, col, dinv, b2, outp, N);
}

// Round 11
// 285.986 us; speedup vs baseline: 7.8225x; 1.0914x over previous
//
#include <hip/hip_runtime.h>
#include <hip/hip_fp16.h>

// GCN 2-layer via CSR gather. G tables stored fp16 (halves random-gather bytes;
// values bounded ~±4, fp16 ulp ~1e-3 -> abs err ~2e-3 << 1e-2 threshold).
// out = dinv ⊙ (A · (dinv ⊙ (relu(dinv ⊙ (A · (dinv ⊙ (x@W1))) + b1) @ W2))) + b2

constexpr int DIN = 128;

// ---- small utility kernels -------------------------------------------------
__global__ void zero_int_k(int* __restrict__ p, int n) {
    int i = blockIdx.x * 256 + threadIdx.x;
    if (i < n) p[i] = 0;
}

__global__ void copy_int_k(const int* __restrict__ a, int* __restrict__ b, int n) {
    int i = blockIdx.x * 256 + threadIdx.x;
    if (i < n) b[i] = a[i];
}

__global__ void count_deg_k(const int* __restrict__ dst, int* __restrict__ cnt, int e) {
    int i = blockIdx.x * 256 + threadIdx.x;
    if (i < e) atomicAdd(&cnt[dst[i]], 1);
}

__global__ void dinv_k(const int* __restrict__ cnt, float* __restrict__ dinv, int n) {
    int i = blockIdx.x * 256 + threadIdx.x;
    if (i < n) dinv[i] = rsqrtf((float)cnt[i] + 1.0f);   // +1 self-loop
}

// ---- hierarchical exclusive scan: rowptr[0..n] from cnt[0..n-1] ------------
__global__ __launch_bounds__(256) void scan1_k(const int* __restrict__ cnt,
                                               int* __restrict__ rowptr,
                                               int* __restrict__ bsum,
                                               int n_out, int n_cnt) {
    __shared__ int wsum[4];
    const int tid  = threadIdx.x;
    const int lane = tid & 63;
    const int wv   = tid >> 6;
    const int base = blockIdx.x * 1024 + tid * 4;

    int v0 = (base + 0 < n_cnt) ? cnt[base + 0] : 0;
    int v1 = (base + 1 < n_cnt) ? cnt[base + 1] : 0;
    int v2 = (base + 2 < n_cnt) ? cnt[base + 2] : 0;
    int v3 = (base + 3 < n_cnt) ? cnt[base + 3] : 0;
    int tsum = v0 + v1 + v2 + v3;

    int incl = tsum;
    for (int d = 1; d < 64; d <<= 1) {
        int t = __shfl_up(incl, d, 64);
        if (lane >= d) incl += t;
    }
    if (lane == 63) wsum[wv] = incl;
    __syncthreads();
    int woff = 0;
    for (int w = 0; w < wv; ++w) woff += wsum[w];
    int excl = woff + incl - tsum;

    int e0 = excl;
    int e1 = e0 + v0;
    int e2 = e1 + v1;
    int e3 = e2 + v2;
    if (base + 0 < n_out) rowptr[base + 0] = e0;
    if (base + 1 < n_out) rowptr[base + 1] = e1;
    if (base + 2 < n_out) rowptr[base + 2] = e2;
    if (base + 3 < n_out) rowptr[base + 3] = e3;

    if (tid == 255) bsum[blockIdx.x] = woff + incl;
}

__global__ __launch_bounds__(1024) void scan2_k(int* __restrict__ bsum, int nb) {
    __shared__ int sh[1024];
    const int t = threadIdx.x;
    int v = (t < nb) ? bsum[t] : 0;
    sh[t] = v;
    __syncthreads();
    for (int d = 1; d < 1024; d <<= 1) {
        int x = (t >= d) ? sh[t - d] : 0;
        __syncthreads();
        sh[t] += x;
        __syncthreads();
    }
    if (t < nb) bsum[t] = sh[t] - v;
}

__global__ void scan3_k(int* __restrict__ rowptr, const int* __restrict__ bsum, int n_out) {
    int i = blockIdx.x * 256 + threadIdx.x;
    if (i < n_out) rowptr[i] += bsum[i >> 10];
}

// fill: cur pre-initialized to rowptr copy -> one random atomic + one write per edge
__global__ void fill_k(const int* __restrict__ src, const int* __restrict__ dst,
                       int* __restrict__ cur, int* __restrict__ col, int e) {
    int i = blockIdx.x * 256 + threadIdx.x;
    if (i >= e) return;
    int pos = atomicAdd(&cur[dst[i]], 1);
    col[pos] = src[i];
}

// ---- fused GEMM + row scale -> fp16:  G = fp16(dinv[:,None] * (X @ W)) -----
// W read from global (L2-resident, broadcast); X staged in LDS (32 KB).
template <int DOUT>
__global__ __launch_bounds__(256, 4) void gemm_scale_k(
    const float* __restrict__ X, const float* __restrict__ W,
    const float* __restrict__ dinv, __half* __restrict__ G, int N)
{
    constexpr int TM = 64;
    constexpr int C4 = DOUT / 4;
    constexpr int GROUPS = 256 / C4;
    constexpr int RPT = TM / GROUPS;

    __shared__ float sX[TM * DIN];

    const int tid  = threadIdx.x;
    const int base = blockIdx.x * TM;
    const float4* Wv = reinterpret_cast<const float4*>(W);

    for (int idx = tid; idx < TM * DIN / 4; idx += 256) {
        int row  = idx / (DIN / 4);
        int grow = base + row;
        float4 v = make_float4(0.f, 0.f, 0.f, 0.f);
        if (grow < N)
            v = reinterpret_cast<const float4*>(X)[(size_t)grow * (DIN / 4) + (idx % (DIN / 4))];
        reinterpret_cast<float4*>(sX)[idx] = v;
    }
    __syncthreads();

    const int cq = tid % C4;
    const int rg = tid / C4;

    float4 acc[RPT];
#pragma unroll
    for (int r = 0; r < RPT; ++r) acc[r] = make_float4(0.f, 0.f, 0.f, 0.f);

#pragma unroll 4
    for (int k = 0; k < DIN; ++k) {
        float4 w = Wv[k * C4 + cq];
#pragma unroll
        for (int r = 0; r < RPT; ++r) {
            float xv = sX[(rg + r * GROUPS) * DIN + k];
            acc[r].x = fmaf(xv, w.x, acc[r].x);
            acc[r].y = fmaf(xv, w.y, acc[r].y);
            acc[r].z = fmaf(xv, w.z, acc[r].z);
            acc[r].w = fmaf(xv, w.w, acc[r].w);
        }
    }

#pragma unroll
    for (int r = 0; r < RPT; ++r) {
        int row = base + rg + r * GROUPS;
        if (row < N) {
            float dv = dinv[row];
            __half2 p0 = __floats2half2_rn(acc[r].x * dv, acc[r].y * dv);
            __half2 p1 = __floats2half2_rn(acc[r].z * dv, acc[r].w * dv);
            uint2 packed = make_uint2(*reinterpret_cast<unsigned*>(&p0),
                                      *reinterpret_cast<unsigned*>(&p1));
            *reinterpret_cast<uint2*>(G + (size_t)row * DOUT + cq * 4) = packed;
        }
    }
}

// ---- gather (fp16 table, f32 accumulate/output) ----------------------------
// Row = D halves. Each lane loads 8 halves (16 B); Q = D/8 lanes per row,
// NS = 64/Q edge slots per wave. shfl_xor tree combines slots.
template <int D, bool RELU>
__global__ __launch_bounds__(256) void gather_k(
    const __half* __restrict__ G, const int* __restrict__ rowptr,
    const int* __restrict__ col, const float* __restrict__ dinv,
    const float* __restrict__ bias, float* __restrict__ out, int N)
{
    constexpr int Q  = D / 8;    // lanes per row: 16 (D=128) / 8 (D=64)
    constexpr int NS = 64 / Q;   // edge slots: 4 / 8

    const int wave = (blockIdx.x * 256 + threadIdx.x) >> 6;
    const int lane = threadIdx.x & 63;
    if (wave >= N) return;
    const int node = wave;
    const int q    = lane % Q;
    const int slot = lane / Q;

    const uint4* G4 = reinterpret_cast<const uint4*>(G);   // 16 B = 8 halves

    float acc[8];
#pragma unroll
    for (int k = 0; k < 8; ++k) acc[k] = 0.f;

    auto accum = [&](uint4 raw) {
        const __half2* hp = reinterpret_cast<const __half2*>(&raw);
#pragma unroll
        for (int p = 0; p < 4; ++p) {
            float2 f = __half22float2(hp[p]);
            acc[2 * p]     += f.x;
            acc[2 * p + 1] += f.y;
        }
    };

    if (slot == 0) accum(G4[(size_t)node * Q + q]);        // self-loop
    const int beg = rowptr[node], end = rowptr[node + 1];
    int j = beg;

    for (; j + 4 * NS <= end; j += 4 * NS) {
        int s0 = col[j + 0 * NS + slot];
        int s1 = col[j + 1 * NS + slot];
        int s2 = col[j + 2 * NS + slot];
        int s3 = col[j + 3 * NS + slot];
        uint4 v0 = G4[(size_t)s0 * Q + q];
        uint4 v1 = G4[(size_t)s1 * Q + q];
        uint4 v2 = G4[(size_t)s2 * Q + q];
        uint4 v3 = G4[(size_t)s3 * Q + q];
        accum(v0); accum(v1); accum(v2); accum(v3);
    }
    for (; j + NS <= end; j += NS) {
        accum(G4[(size_t)col[j + slot] * Q + q]);
    }
    {
        int rem = end - j;
        if (slot < rem) accum(G4[(size_t)col[j + slot] * Q + q]);
    }

#pragma unroll
    for (int d = Q; d < 64; d <<= 1) {
#pragma unroll
        for (int k = 0; k < 8; ++k) acc[k] += __shfl_xor(acc[k], d, 64);
    }

    if (lane < Q) {
        float dv = dinv[node];
        float4 o0, o1;
        const float4* bb = reinterpret_cast<const float4*>(bias + q * 8);
        float4 b0 = bb[0], b1 = bb[1];
        o0.x = dv * acc[0] + b0.x;  o0.y = dv * acc[1] + b0.y;
        o0.z = dv * acc[2] + b0.z;  o0.w = dv * acc[3] + b0.w;
        o1.x = dv * acc[4] + b1.x;  o1.y = dv * acc[5] + b1.y;
        o1.z = dv * acc[6] + b1.z;  o1.w = dv * acc[7] + b1.w;
        if constexpr (RELU) {
            o0.x = fmaxf(o0.x, 0.f); o0.y = fmaxf(o0.y, 0.f);
            o0.z = fmaxf(o0.z, 0.f); o0.w = fmaxf(o0.w, 0.f);
            o1.x = fmaxf(o1.x, 0.f); o1.y = fmaxf(o1.y, 0.f);
            o1.z = fmaxf(o1.z, 0.f); o1.w = fmaxf(o1.w, 0.f);
        }
        float4* op = reinterpret_cast<float4*>(out + (size_t)node * D + q * 8);
        op[0] = o0;
        op[1] = o1;
    }
}

static inline size_t align256(size_t x) { return (x + 255) & ~size_t(255); }

extern "C" void kernel_launch(void* const* d_in, const int* in_sizes, int n_in,
                              void* d_out, int out_size, void* d_ws, size_t ws_size,
                              hipStream_t stream) {
    const float* e_prev = (const float*)d_in[0];
    const int*   eidx   = (const int*)d_in[1];
    const float* W1     = (const float*)d_in[2];
    const float* b1     = (const float*)d_in[3];
    const float* W2     = (const float*)d_in[4];
    const float* b2     = (const float*)d_in[5];

    const int dh   = in_sizes[3];            // 128
    const int din  = in_sizes[2] / dh;       // 128
    const int N    = in_sizes[0] / din;      // 50000
    const int E    = in_sizes[1] / 2;        // 800000
    (void)dh;

    const int* src = eidx;
    const int* dst = eidx + E;

    // workspace layout
    char* ws = (char*)d_ws;
    size_t off = 0;
    int*    cnt    = (int*)(ws + off);    off = align256(off + (size_t)N * 4);
    int*    cur    = (int*)(ws + off);    off = align256(off + (size_t)N * 4);
    float*  dinv   = (float*)(ws + off);  off = align256(off + (size_t)N * 4);
    int*    rowptr = (int*)(ws + off);    off = align256(off + (size_t)(N + 1) * 4);
    int*    bsum   = (int*)(ws + off);    off = align256(off + (size_t)1024 * 4);
    int*    col    = (int*)(ws + off);    off = align256(off + (size_t)E * 4);
    __half* gh     = (__half*)(ws + off); off = align256(off + (size_t)N * DIN * 2);  // fp16 G
    float*  x2     = (float*)(ws + off);  off = align256(off + (size_t)N * DIN * 4);  // f32 x2
    (void)ws_size;

    float* outp = (float*)d_out;

    const int T = 256;
    const int gN = (N + T - 1) / T;
    const int gE = (E + T - 1) / T;
    const int gW = (N + 3) / 4;              // 4 waves per 256-thread block
    const int n_out = N + 1;
    const int nb = (n_out + 1023) / 1024;

    // ---- CSR build ----
    zero_int_k<<<gN, T, 0, stream>>>(cnt, N);
    count_deg_k<<<gE, T, 0, stream>>>(dst, cnt, E);
    dinv_k<<<gN, T, 0, stream>>>(cnt, dinv, N);
    scan1_k<<<nb, T, 0, stream>>>(cnt, rowptr, bsum, n_out, N);
    scan2_k<<<1, 1024, 0, stream>>>(bsum, nb);
    scan3_k<<<(n_out + T - 1) / T, T, 0, stream>>>(rowptr, bsum, n_out);
    copy_int_k<<<gN, T, 0, stream>>>(rowptr, cur, N);
    fill_k<<<gE, T, 0, stream>>>(src, dst, cur, col, E);

    // ---- layer 1 ----
    gemm_scale_k<128><<<(N + 63) / 64, T, 0, stream>>>(e_prev, W1, dinv, gh, N);
    gather_k<128, true><<<gW, T, 0, stream>>>(gh, rowptr, col, dinv, b1, x2, N);

    // ---- layer 2 ----
    gemm_scale_k<64><<<(N + 63) / 64, T, 0, stream>>>(x2, W2, dinv, gh, N);
    gather_k<64, false><<<gW, T, 0, stream>>>(gh, rowptr, col, dinv, b2, outp, N);
}

// Round 14
// 250.836 us; speedup vs baseline: 8.9186x; 1.1401x over previous
//
#include <hip/hip_runtime.h>
#include <hip/hip_fp16.h>

// GCN 2-layer via CSR gather. G tables stored fp16 (halves random-gather bytes).
// CSR build uses rank-capture: the degree-count atomic's return value IS the
// edge's slot within its dst bucket -> fill needs no atomic.
// out = dinv ⊙ (A · (dinv ⊙ (relu(dinv ⊙ (A · (dinv ⊙ (x@W1))) + b1) @ W2))) + b2

constexpr int DIN = 128;

// ---- small utility kernels -------------------------------------------------
__global__ void zero_int_k(int* __restrict__ p, int n) {
    int i = blockIdx.x * 256 + threadIdx.x;
    if (i < n) p[i] = 0;
}

// degree histogram + per-edge rank capture
__global__ void count_deg_k(const int* __restrict__ dst, int* __restrict__ cnt,
                            int* __restrict__ rank, int e) {
    int i = blockIdx.x * 256 + threadIdx.x;
    if (i < e) rank[i] = atomicAdd(&cnt[dst[i]], 1);
}

__global__ void dinv_k(const int* __restrict__ cnt, float* __restrict__ dinv, int n) {
    int i = blockIdx.x * 256 + threadIdx.x;
    if (i < n) dinv[i] = rsqrtf((float)cnt[i] + 1.0f);   // +1 self-loop
}

// ---- hierarchical exclusive scan: rowptr[0..n] from cnt[0..n-1] ------------
__global__ __launch_bounds__(256) void scan1_k(const int* __restrict__ cnt,
                                               int* __restrict__ rowptr,
                                               int* __restrict__ bsum,
                                               int n_out, int n_cnt) {
    __shared__ int wsum[4];
    const int tid  = threadIdx.x;
    const int lane = tid & 63;
    const int wv   = tid >> 6;
    const int base = blockIdx.x * 1024 + tid * 4;

    int v0 = (base + 0 < n_cnt) ? cnt[base + 0] : 0;
    int v1 = (base + 1 < n_cnt) ? cnt[base + 1] : 0;
    int v2 = (base + 2 < n_cnt) ? cnt[base + 2] : 0;
    int v3 = (base + 3 < n_cnt) ? cnt[base + 3] : 0;
    int tsum = v0 + v1 + v2 + v3;

    int incl = tsum;
    for (int d = 1; d < 64; d <<= 1) {
        int t = __shfl_up(incl, d, 64);
        if (lane >= d) incl += t;
    }
    if (lane == 63) wsum[wv] = incl;
    __syncthreads();
    int woff = 0;
    for (int w = 0; w < wv; ++w) woff += wsum[w];
    int excl = woff + incl - tsum;

    int e0 = excl;
    int e1 = e0 + v0;
    int e2 = e1 + v1;
    int e3 = e2 + v2;
    if (base + 0 < n_out) rowptr[base + 0] = e0;
    if (base + 1 < n_out) rowptr[base + 1] = e1;
    if (base + 2 < n_out) rowptr[base + 2] = e2;
    if (base + 3 < n_out) rowptr[base + 3] = e3;

    if (tid == 255) bsum[blockIdx.x] = woff + incl;
}

__global__ __launch_bounds__(1024) void scan2_k(int* __restrict__ bsum, int nb) {
    __shared__ int sh[1024];
    const int t = threadIdx.x;
    int v = (t < nb) ? bsum[t] : 0;
    sh[t] = v;
    __syncthreads();
    for (int d = 1; d < 1024; d <<= 1) {
        int x = (t >= d) ? sh[t - d] : 0;
        __syncthreads();
        sh[t] += x;
        __syncthreads();
    }
    if (t < nb) bsum[t] = sh[t] - v;
}

__global__ void scan3_k(int* __restrict__ rowptr, const int* __restrict__ bsum, int n_out) {
    int i = blockIdx.x * 256 + threadIdx.x;
    if (i < n_out) rowptr[i] += bsum[i >> 10];
}

// fill: no atomic — pos = rowptr[dst] + rank (rank captured during count)
__global__ void fill_k(const int* __restrict__ src, const int* __restrict__ dst,
                       const int* __restrict__ rowptr, const int* __restrict__ rank,
                       int* __restrict__ col, int e) {
    int i = blockIdx.x * 256 + threadIdx.x;
    if (i >= e) return;
    int pos = rowptr[dst[i]] + rank[i];
    col[pos] = src[i];
}

// ---- fused GEMM + row scale -> fp16:  G = fp16(dinv[:,None] * (X @ W)) -----
template <int DOUT>
__global__ __launch_bounds__(256, 4) void gemm_scale_k(
    const float* __restrict__ X, const float* __restrict__ W,
    const float* __restrict__ dinv, __half* __restrict__ G, int N)
{
    constexpr int TM = 64;
    constexpr int C4 = DOUT / 4;
    constexpr int GROUPS = 256 / C4;
    constexpr int RPT = TM / GROUPS;

    __shared__ float sX[TM * DIN];

    const int tid  = threadIdx.x;
    const int base = blockIdx.x * TM;
    const float4* Wv = reinterpret_cast<const float4*>(W);

    for (int idx = tid; idx < TM * DIN / 4; idx += 256) {
        int row  = idx / (DIN / 4);
        int grow = base + row;
        float4 v = make_float4(0.f, 0.f, 0.f, 0.f);
        if (grow < N)
            v = reinterpret_cast<const float4*>(X)[(size_t)grow * (DIN / 4) + (idx % (DIN / 4))];
        reinterpret_cast<float4*>(sX)[idx] = v;
    }
    __syncthreads();

    const int cq = tid % C4;
    const int rg = tid / C4;

    float4 acc[RPT];
#pragma unroll
    for (int r = 0; r < RPT; ++r) acc[r] = make_float4(0.f, 0.f, 0.f, 0.f);

#pragma unroll 4
    for (int k = 0; k < DIN; ++k) {
        float4 w = Wv[k * C4 + cq];
#pragma unroll
        for (int r = 0; r < RPT; ++r) {
            float xv = sX[(rg + r * GROUPS) * DIN + k];
            acc[r].x = fmaf(xv, w.x, acc[r].x);
            acc[r].y = fmaf(xv, w.y, acc[r].y);
            acc[r].z = fmaf(xv, w.z, acc[r].z);
            acc[r].w = fmaf(xv, w.w, acc[r].w);
        }
    }

#pragma unroll
    for (int r = 0; r < RPT; ++r) {
        int row = base + rg + r * GROUPS;
        if (row < N) {
            float dv = dinv[row];
            __half2 p0 = __floats2half2_rn(acc[r].x * dv, acc[r].y * dv);
            __half2 p1 = __floats2half2_rn(acc[r].z * dv, acc[r].w * dv);
            uint2 packed = make_uint2(*reinterpret_cast<unsigned*>(&p0),
                                      *reinterpret_cast<unsigned*>(&p1));
            *reinterpret_cast<uint2*>(G + (size_t)row * DOUT + cq * 4) = packed;
        }
    }
}

// ---- gather (fp16 table, f32 accumulate/output) ----------------------------
template <int D, bool RELU>
__global__ __launch_bounds__(256) void gather_k(
    const __half* __restrict__ G, const int* __restrict__ rowptr,
    const int* __restrict__ col, const float* __restrict__ dinv,
    const float* __restrict__ bias, float* __restrict__ out, int N)
{
    constexpr int Q  = D / 8;    // lanes per row: 16 (D=128) / 8 (D=64)
    constexpr int NS = 64 / Q;   // edge slots: 4 / 8

    const int wave = (blockIdx.x * 256 + threadIdx.x) >> 6;
    const int lane = threadIdx.x & 63;
    if (wave >= N) return;
    const int node = wave;
    const int q    = lane % Q;
    const int slot = lane / Q;

    const uint4* G4 = reinterpret_cast<const uint4*>(G);   // 16 B = 8 halves

    float acc[8];
#pragma unroll
    for (int k = 0; k < 8; ++k) acc[k] = 0.f;

    auto accum = [&](uint4 raw) {
        const __half2* hp = reinterpret_cast<const __half2*>(&raw);
#pragma unroll
        for (int p = 0; p < 4; ++p) {
            float2 f = __half22float2(hp[p]);
            acc[2 * p]     += f.x;
            acc[2 * p + 1] += f.y;
        }
    };

    if (slot == 0) accum(G4[(size_t)node * Q + q]);        // self-loop
    const int beg = rowptr[node], end = rowptr[node + 1];
    int j = beg;

    for (; j + 4 * NS <= end; j += 4 * NS) {
        int s0 = col[j + 0 * NS + slot];
        int s1 = col[j + 1 * NS + slot];
        int s2 = col[j + 2 * NS + slot];
        int s3 = col[j + 3 * NS + slot];
        uint4 v0 = G4[(size_t)s0 * Q + q];
        uint4 v1 = G4[(size_t)s1 * Q + q];
        uint4 v2 = G4[(size_t)s2 * Q + q];
        uint4 v3 = G4[(size_t)s3 * Q + q];
        accum(v0); accum(v1); accum(v2); accum(v3);
    }
    for (; j + NS <= end; j += NS) {
        accum(G4[(size_t)col[j + slot] * Q + q]);
    }
    {
        int rem = end - j;
        if (slot < rem) accum(G4[(size_t)col[j + slot] * Q + q]);
    }

#pragma unroll
    for (int d = Q; d < 64; d <<= 1) {
#pragma unroll
        for (int k = 0; k < 8; ++k) acc[k] += __shfl_xor(acc[k], d, 64);
    }

    if (lane < Q) {
        float dv = dinv[node];
        float4 o0, o1;
        const float4* bb = reinterpret_cast<const float4*>(bias + q * 8);
        float4 b0 = bb[0], b1 = bb[1];
        o0.x = dv * acc[0] + b0.x;  o0.y = dv * acc[1] + b0.y;
        o0.z = dv * acc[2] + b0.z;  o0.w = dv * acc[3] + b0.w;
        o1.x = dv * acc[4] + b1.x;  o1.y = dv * acc[5] + b1.y;
        o1.z = dv * acc[6] + b1.z;  o1.w = dv * acc[7] + b1.w;
        if constexpr (RELU) {
            o0.x = fmaxf(o0.x, 0.f); o0.y = fmaxf(o0.y, 0.f);
            o0.z = fmaxf(o0.z, 0.f); o0.w = fmaxf(o0.w, 0.f);
            o1.x = fmaxf(o1.x, 0.f); o1.y = fmaxf(o1.y, 0.f);
            o1.z = fmaxf(o1.z, 0.f); o1.w = fmaxf(o1.w, 0.f);
        }
        float4* op = reinterpret_cast<float4*>(out + (size_t)node * D + q * 8);
        op[0] = o0;
        op[1] = o1;
    }
}

static inline size_t align256(size_t x) { return (x + 255) & ~size_t(255); }

extern "C" void kernel_launch(void* const* d_in, const int* in_sizes, int n_in,
                              void* d_out, int out_size, void* d_ws, size_t ws_size,
                              hipStream_t stream) {
    const float* e_prev = (const float*)d_in[0];
    const int*   eidx   = (const int*)d_in[1];
    const float* W1     = (const float*)d_in[2];
    const float* b1     = (const float*)d_in[3];
    const float* W2     = (const float*)d_in[4];
    const float* b2     = (const float*)d_in[5];

    const int dh   = in_sizes[3];            // 128
    const int din  = in_sizes[2] / dh;       // 128
    const int N    = in_sizes[0] / din;      // 50000
    const int E    = in_sizes[1] / 2;        // 800000
    (void)dh;

    const int* src = eidx;
    const int* dst = eidx + E;

    // workspace layout
    char* ws = (char*)d_ws;
    size_t off = 0;
    int*    cnt    = (int*)(ws + off);    off = align256(off + (size_t)N * 4);
    float*  dinv   = (float*)(ws + off);  off = align256(off + (size_t)N * 4);
    int*    rowptr = (int*)(ws + off);    off = align256(off + (size_t)(N + 1) * 4);
    int*    bsum   = (int*)(ws + off);    off = align256(off + (size_t)1024 * 4);
    int*    col    = (int*)(ws + off);    off = align256(off + (size_t)E * 4);
    int*    rank   = (int*)(ws + off);    off = align256(off + (size_t)E * 4);
    __half* gh     = (__half*)(ws + off); off = align256(off + (size_t)N * DIN * 2);  // fp16 G
    float*  x2     = (float*)(ws + off);  off = align256(off + (size_t)N * DIN * 4);  // f32 x2
    (void)ws_size;

    float* outp = (float*)d_out;

    const int T = 256;
    const int gN = (N + T - 1) / T;
    const int gE = (E + T - 1) / T;
    const int gW = (N + 3) / 4;              // 4 waves per 256-thread block
    const int n_out = N + 1;
    const int nb = (n_out + 1023) / 1024;

    // ---- CSR build ----
    zero_int_k<<<gN, T, 0, stream>>>(cnt, N);
    count_deg_k<<<gE, T, 0, stream>>>(dst, cnt, rank, E);
    dinv_k<<<gN, T, 0, stream>>>(cnt, dinv, N);
    scan1_k<<<nb, T, 0, stream>>>(cnt, rowptr, bsum, n_out, N);
    scan2_k<<<1, 1024, 0, stream>>>(bsum, nb);
    scan3_k<<<(n_out + T - 1) / T, T, 0, stream>>>(rowptr, bsum, n_out);
    fill_k<<<gE, T, 0, stream>>>(src, dst, rowptr, rank, col, E);

    // ---- layer 1 ----
    gemm_scale_k<128><<<(N + 63) / 64, T, 0, stream>>>(e_prev, W1, dinv, gh, N);
    gather_k<128, true><<<gW, T, 0, stream>>>(gh, rowptr, col, dinv, b1, x2, N);

    // ---- layer 2 ----
    gemm_scale_k<64><<<(N + 63) / 64, T, 0, stream>>>(x2, W2, dinv, gh, N);
    gather_k<64, false><<<gW, T, 0, stream>>>(gh, rowptr, col, dinv, b2, outp, N);
}

// Round 15
// 245.514 us; speedup vs baseline: 9.1120x; 1.0217x over previous
//
#include <hip/hip_runtime.h>
#include <hip/hip_fp16.h>

// GCN 2-layer via CSR gather. G tables AND x2 intermediate in fp16
// (halves random-gather + intermediate bytes). CSR build: rank-capture
// (degree atomic's return = slot) -> fill needs no atomic.
// out = dinv ⊙ (A · (dinv ⊙ (relu(dinv ⊙ (A · (dinv ⊙ (x@W1))) + b1) @ W2))) + b2

constexpr int DIN = 128;

// ---- degree histogram + per-edge rank capture (2 edges/thread) -------------
__global__ void count_deg_k(const int* __restrict__ dst, int* __restrict__ cnt,
                            int* __restrict__ rank, int e2, int e) {
    int i = blockIdx.x * 256 + threadIdx.x;
    if (i >= e2) return;
    int2 d = reinterpret_cast<const int2*>(dst)[i];
    int r0 = atomicAdd(&cnt[d.x], 1);
    int r1 = (2 * i + 1 < e) ? atomicAdd(&cnt[d.y], 1) : 0;
    reinterpret_cast<int2*>(rank)[i] = make_int2(r0, r1);
}

// ---- hierarchical exclusive scan + fused dinv ------------------------------
__global__ __launch_bounds__(256) void scan1_k(const int* __restrict__ cnt,
                                               int* __restrict__ rowptr,
                                               int* __restrict__ bsum,
                                               float* __restrict__ dinv,
                                               int n_out, int n_cnt) {
    __shared__ int wsum[4];
    const int tid  = threadIdx.x;
    const int lane = tid & 63;
    const int wv   = tid >> 6;
    const int base = blockIdx.x * 1024 + tid * 4;

    int v0 = (base + 0 < n_cnt) ? cnt[base + 0] : 0;
    int v1 = (base + 1 < n_cnt) ? cnt[base + 1] : 0;
    int v2 = (base + 2 < n_cnt) ? cnt[base + 2] : 0;
    int v3 = (base + 3 < n_cnt) ? cnt[base + 3] : 0;
    int tsum = v0 + v1 + v2 + v3;

    // fused: dinv = rsqrt(deg + 1 self-loop)
    if (base + 0 < n_cnt) dinv[base + 0] = rsqrtf((float)v0 + 1.0f);
    if (base + 1 < n_cnt) dinv[base + 1] = rsqrtf((float)v1 + 1.0f);
    if (base + 2 < n_cnt) dinv[base + 2] = rsqrtf((float)v2 + 1.0f);
    if (base + 3 < n_cnt) dinv[base + 3] = rsqrtf((float)v3 + 1.0f);

    int incl = tsum;
    for (int d = 1; d < 64; d <<= 1) {
        int t = __shfl_up(incl, d, 64);
        if (lane >= d) incl += t;
    }
    if (lane == 63) wsum[wv] = incl;
    __syncthreads();
    int woff = 0;
    for (int w = 0; w < wv; ++w) woff += wsum[w];
    int excl = woff + incl - tsum;

    int e0 = excl;
    int e1 = e0 + v0;
    int e2 = e1 + v1;
    int e3 = e2 + v2;
    if (base + 0 < n_out) rowptr[base + 0] = e0;
    if (base + 1 < n_out) rowptr[base + 1] = e1;
    if (base + 2 < n_out) rowptr[base + 2] = e2;
    if (base + 3 < n_out) rowptr[base + 3] = e3;

    if (tid == 255) bsum[blockIdx.x] = woff + incl;
}

__global__ __launch_bounds__(1024) void scan2_k(int* __restrict__ bsum, int nb) {
    __shared__ int sh[1024];
    const int t = threadIdx.x;
    int v = (t < nb) ? bsum[t] : 0;
    sh[t] = v;
    __syncthreads();
    for (int d = 1; d < 1024; d <<= 1) {
        int x = (t >= d) ? sh[t - d] : 0;
        __syncthreads();
        sh[t] += x;
        __syncthreads();
    }
    if (t < nb) bsum[t] = sh[t] - v;
}

__global__ void scan3_k(int* __restrict__ rowptr, const int* __restrict__ bsum, int n_out) {
    int i = blockIdx.x * 256 + threadIdx.x;
    if (i < n_out) rowptr[i] += bsum[i >> 10];
}

// fill: no atomic — pos = rowptr[dst] + rank  (2 edges/thread)
__global__ void fill_k(const int* __restrict__ src, const int* __restrict__ dst,
                       const int* __restrict__ rowptr, const int* __restrict__ rank,
                       int* __restrict__ col, int e2, int e) {
    int i = blockIdx.x * 256 + threadIdx.x;
    if (i >= e2) return;
    int2 d = reinterpret_cast<const int2*>(dst)[i];
    int2 r = reinterpret_cast<const int2*>(rank)[i];
    int2 s = reinterpret_cast<const int2*>(src)[i];
    col[rowptr[d.x] + r.x] = s.x;
    if (2 * i + 1 < e) col[rowptr[d.y] + r.y] = s.y;
}

// ---- fused GEMM + row scale -> fp16:  G = fp16(dinv[:,None] * (X @ W)) -----
// TIN = float (layer 1, e_prev) or __half (layer 2, x2h).
template <typename TIN, int DOUT>
__global__ __launch_bounds__(256, 4) void gemm_scale_k(
    const TIN* __restrict__ X, const float* __restrict__ W,
    const float* __restrict__ dinv, __half* __restrict__ G, int N)
{
    constexpr int TM = 64;
    constexpr int C4 = DOUT / 4;
    constexpr int GROUPS = 256 / C4;
    constexpr int RPT = TM / GROUPS;

    __shared__ TIN sX[TM * DIN];        // 32 KB (f32) / 16 KB (fp16)

    const int tid  = threadIdx.x;
    const int base = blockIdx.x * TM;
    const float4* Wv = reinterpret_cast<const float4*>(W);

    // stage X: 16 B per thread-iter
    constexpr int EPL = 16 / sizeof(TIN);            // elems per 16B: 4 / 8
    for (int idx = tid; idx < TM * DIN / EPL; idx += 256) {
        int row  = idx / (DIN / EPL);
        int grow = base + row;
        uint4 v = make_uint4(0u, 0u, 0u, 0u);
        if (grow < N)
            v = reinterpret_cast<const uint4*>(X)[(size_t)grow * (DIN / EPL) + (idx % (DIN / EPL))];
        reinterpret_cast<uint4*>(sX)[idx] = v;
    }
    __syncthreads();

    const int cq = tid % C4;
    const int rg = tid / C4;

    float4 acc[RPT];
#pragma unroll
    for (int r = 0; r < RPT; ++r) acc[r] = make_float4(0.f, 0.f, 0.f, 0.f);

#pragma unroll 4
    for (int k = 0; k < DIN; ++k) {
        float4 w = Wv[k * C4 + cq];
#pragma unroll
        for (int r = 0; r < RPT; ++r) {
            float xv;
            if constexpr (sizeof(TIN) == 4) xv = ((const float*)sX)[(rg + r * GROUPS) * DIN + k];
            else                            xv = __half2float(((const __half*)sX)[(rg + r * GROUPS) * DIN + k]);
            acc[r].x = fmaf(xv, w.x, acc[r].x);
            acc[r].y = fmaf(xv, w.y, acc[r].y);
            acc[r].z = fmaf(xv, w.z, acc[r].z);
            acc[r].w = fmaf(xv, w.w, acc[r].w);
        }
    }

#pragma unroll
    for (int r = 0; r < RPT; ++r) {
        int row = base + rg + r * GROUPS;
        if (row < N) {
            float dv = dinv[row];
            __half2 p0 = __floats2half2_rn(acc[r].x * dv, acc[r].y * dv);
            __half2 p1 = __floats2half2_rn(acc[r].z * dv, acc[r].w * dv);
            uint2 packed = make_uint2(*reinterpret_cast<unsigned*>(&p0),
                                      *reinterpret_cast<unsigned*>(&p1));
            *reinterpret_cast<uint2*>(G + (size_t)row * DOUT + cq * 4) = packed;
        }
    }
}

// ---- gather (fp16 table, f32 accumulate; TOUT = __half or float) -----------
template <int D, bool RELU, typename TOUT>
__global__ __launch_bounds__(256) void gather_k(
    const __half* __restrict__ G, const int* __restrict__ rowptr,
    const int* __restrict__ col, const float* __restrict__ dinv,
    const float* __restrict__ bias, TOUT* __restrict__ out, int N)
{
    constexpr int Q  = D / 8;    // lanes per row: 16 (D=128) / 8 (D=64)
    constexpr int NS = 64 / Q;   // edge slots: 4 / 8

    const int wave = (blockIdx.x * 256 + threadIdx.x) >> 6;
    const int lane = threadIdx.x & 63;
    if (wave >= N) return;
    const int node = wave;
    const int q    = lane % Q;
    const int slot = lane / Q;

    const uint4* G4 = reinterpret_cast<const uint4*>(G);   // 16 B = 8 halves

    float acc[8];
#pragma unroll
    for (int k = 0; k < 8; ++k) acc[k] = 0.f;

    auto accum = [&](uint4 raw) {
        const __half2* hp = reinterpret_cast<const __half2*>(&raw);
#pragma unroll
        for (int p = 0; p < 4; ++p) {
            float2 f = __half22float2(hp[p]);
            acc[2 * p]     += f.x;
            acc[2 * p + 1] += f.y;
        }
    };

    if (slot == 0) accum(G4[(size_t)node * Q + q]);        // self-loop
    const int beg = rowptr[node], end = rowptr[node + 1];
    int j = beg;

    for (; j + 4 * NS <= end; j += 4 * NS) {
        int s0 = col[j + 0 * NS + slot];
        int s1 = col[j + 1 * NS + slot];
        int s2 = col[j + 2 * NS + slot];
        int s3 = col[j + 3 * NS + slot];
        uint4 v0 = G4[(size_t)s0 * Q + q];
        uint4 v1 = G4[(size_t)s1 * Q + q];
        uint4 v2 = G4[(size_t)s2 * Q + q];
        uint4 v3 = G4[(size_t)s3 * Q + q];
        accum(v0); accum(v1); accum(v2); accum(v3);
    }
    for (; j + NS <= end; j += NS) {
        accum(G4[(size_t)col[j + slot] * Q + q]);
    }
    {
        int rem = end - j;
        if (slot < rem) accum(G4[(size_t)col[j + slot] * Q + q]);
    }

#pragma unroll
    for (int d = Q; d < 64; d <<= 1) {
#pragma unroll
        for (int k = 0; k < 8; ++k) acc[k] += __shfl_xor(acc[k], d, 64);
    }

    if (lane < Q) {
        float dv = dinv[node];
        const float4* bb = reinterpret_cast<const float4*>(bias + q * 8);
        float4 b0 = bb[0], b1 = bb[1];
        float o[8];
        o[0] = dv * acc[0] + b0.x;  o[1] = dv * acc[1] + b0.y;
        o[2] = dv * acc[2] + b0.z;  o[3] = dv * acc[3] + b0.w;
        o[4] = dv * acc[4] + b1.x;  o[5] = dv * acc[5] + b1.y;
        o[6] = dv * acc[6] + b1.z;  o[7] = dv * acc[7] + b1.w;
        if constexpr (RELU) {
#pragma unroll
            for (int k = 0; k < 8; ++k) o[k] = fmaxf(o[k], 0.f);
        }
        if constexpr (sizeof(TOUT) == 2) {
            __half2 h0 = __floats2half2_rn(o[0], o[1]);
            __half2 h1 = __floats2half2_rn(o[2], o[3]);
            __half2 h2 = __floats2half2_rn(o[4], o[5]);
            __half2 h3 = __floats2half2_rn(o[6], o[7]);
            uint4 packed = make_uint4(*reinterpret_cast<unsigned*>(&h0),
                                      *reinterpret_cast<unsigned*>(&h1),
                                      *reinterpret_cast<unsigned*>(&h2),
                                      *reinterpret_cast<unsigned*>(&h3));
            reinterpret_cast<uint4*>(out)[(size_t)node * Q + q] = packed;
        } else {
            float4* op = reinterpret_cast<float4*>((float*)out + (size_t)node * D + q * 8);
            op[0] = make_float4(o[0], o[1], o[2], o[3]);
            op[1] = make_float4(o[4], o[5], o[6], o[7]);
        }
    }
}

static inline size_t align256(size_t x) { return (x + 255) & ~size_t(255); }

extern "C" void kernel_launch(void* const* d_in, const int* in_sizes, int n_in,
                              void* d_out, int out_size, void* d_ws, size_t ws_size,
                              hipStream_t stream) {
    const float* e_prev = (const float*)d_in[0];
    const int*   eidx   = (const int*)d_in[1];
    const float* W1     = (const float*)d_in[2];
    const float* b1     = (const float*)d_in[3];
    const float* W2     = (const float*)d_in[4];
    const float* b2     = (const float*)d_in[5];

    const int dh   = in_sizes[3];            // 128
    const int din  = in_sizes[2] / dh;       // 128
    const int N    = in_sizes[0] / din;      // 50000
    const int E    = in_sizes[1] / 2;        // 800000
    (void)dh;

    const int* src = eidx;
    const int* dst = eidx + E;

    // workspace layout
    char* ws = (char*)d_ws;
    size_t off = 0;
    int*    cnt    = (int*)(ws + off);    off = align256(off + (size_t)N * 4);
    float*  dinv   = (float*)(ws + off);  off = align256(off + (size_t)N * 4);
    int*    rowptr = (int*)(ws + off);    off = align256(off + (size_t)(N + 1) * 4);
    int*    bsum   = (int*)(ws + off);    off = align256(off + (size_t)1024 * 4);
    int*    col    = (int*)(ws + off);    off = align256(off + (size_t)E * 4);
    int*    rank   = (int*)(ws + off);    off = align256(off + (size_t)E * 4);
    __half* gh     = (__half*)(ws + off); off = align256(off + (size_t)N * DIN * 2);  // fp16 G
    __half* x2h    = (__half*)(ws + off); off = align256(off + (size_t)N * DIN * 2);  // fp16 x2
    (void)ws_size;

    float* outp = (float*)d_out;

    const int T = 256;
    const int gN = (N + T - 1) / T;
    const int E2 = (E + 1) / 2;
    const int gE2 = (E2 + T - 1) / T;
    const int gW = (N + 3) / 4;              // 4 waves per 256-thread block
    const int n_out = N + 1;
    const int nb = (n_out + 1023) / 1024;

    // ---- CSR build ----
    hipMemsetAsync(cnt, 0, (size_t)N * 4, stream);
    count_deg_k<<<gE2, T, 0, stream>>>(dst, cnt, rank, E2, E);
    scan1_k<<<nb, T, 0, stream>>>(cnt, rowptr, bsum, dinv, n_out, N);
    scan2_k<<<1, 1024, 0, stream>>>(bsum, nb);
    scan3_k<<<(n_out + T - 1) / T, T, 0, stream>>>(rowptr, bsum, n_out);
    fill_k<<<gE2, T, 0, stream>>>(src, dst, rowptr, rank, col, E2, E);

    // ---- layer 1 ----
    gemm_scale_k<float, 128><<<(N + 63) / 64, T, 0, stream>>>(e_prev, W1, dinv, gh, N);
    gather_k<128, true, __half><<<gW, T, 0, stream>>>(gh, rowptr, col, dinv, b1, x2h, N);

    // ---- layer 2 ----
    gemm_scale_k<__half, 64><<<(N + 63) / 64, T, 0, stream>>>(x2h, W2, dinv, gh, N);
    gather_k<64, false, float><<<gW, T, 0, stream>>>(gh, rowptr, col, dinv, b2, outp, N);
}